// Round 1
// baseline (325.753 us; speedup 1.0000x reference)
//
#include <hip/hip_runtime.h>
#include <math.h>

#define L_SEQ 4096
#define D_DIM 768
#define C3    2304
#define TAPS  32

typedef __attribute__((ext_vector_type(8))) short bf16x8;
typedef __attribute__((ext_vector_type(4))) float f32x4;

__device__ __forceinline__ unsigned short f2bf(float x) {
  union { float f; unsigned u; } v; v.f = x;
  unsigned r = v.u + 0x7FFF + ((v.u >> 16) & 1);
  return (unsigned short)(r >> 16);
}
__device__ __forceinline__ float bf2f(unsigned short u) {
  union { unsigned u; float f; } v; v.u = ((unsigned)u) << 16; return v.f;
}
__device__ __forceinline__ void gld_lds16(const void* g, void* l) {
  __builtin_amdgcn_global_load_lds((const __attribute__((address_space(1))) void*)g,
                                   (__attribute__((address_space(3))) void*)l, 16, 0, 0);
}

// ---------------- filter: g_tab[c2][t] for t<32 (decay kills lags >=32) ----------------
__global__ __launch_bounds__(256) void filt_kernel(const float* __restrict__ W1,
                                                   const float* __restrict__ b1,
                                                   const float* __restrict__ W2,
                                                   const float* __restrict__ b2,
                                                   const float* __restrict__ f_decay,
                                                   float* __restrict__ g_tab) {
  __shared__ float phi_s[2048];
  const int tid = threadIdx.x;
  #pragma unroll
  for (int it = 0; it < 8; ++it) {
    int idx = tid + it * 256;
    int t = idx >> 6, f = idx & 63;
    float tt = (float)t / 4095.0f;
    float s = b1[f];
    #pragma unroll
    for (int e = 0; e < 33; ++e)
      s += sinf(tt * (float)e * 10.0f) * W1[e * 64 + f];
    phi_s[idx] = sinf(10.0f * s);
  }
  __syncthreads();
  int idx = blockIdx.x * 256 + tid;        // 1536*32
  int c2 = idx >> 5, t = idx & 31;
  float acc = b2[c2];
  #pragma unroll 8
  for (int f = 0; f < 64; ++f)
    acc += phi_s[t * 64 + f] * W2[f * 1536 + c2];
  float r = expf(f_decay[c2]);
  g_tab[idx] = acc * expf(-r * (float)t * (4096.0f / 4095.0f));
}

// ---------------- cvt u: fp32 -> bf16 ----------------
__global__ __launch_bounds__(256) void cvt_kernel(const float* __restrict__ src,
                                                  unsigned short* __restrict__ dst) {
  int idx = (blockIdx.x * 256 + threadIdx.x) * 4;
  float4 v = *(const float4*)&src[idx];
  ushort4 o;
  o.x = f2bf(v.x); o.y = f2bf(v.y); o.z = f2bf(v.z); o.w = f2bf(v.w);
  *(ushort4*)&dst[idx] = o;
}

// ---------------- weight transposes: fp32 [768][C] -> bf16 [C][768] ----------------
__global__ __launch_bounds__(256) void wtrans_kernel(const float* __restrict__ W_in,
                                                     unsigned short* __restrict__ W_inT,
                                                     const float* __restrict__ W_out,
                                                     unsigned short* __restrict__ W_outT) {
  __shared__ float t[32][33];
  const int z = blockIdx.z;
  const float* src = z ? W_out : W_in;
  unsigned short* dst = z ? W_outT : W_inT;
  const int C = z ? 768 : 2304;
  const int c0 = blockIdx.x * 32, r0 = blockIdx.y * 32;
  if (c0 >= C) return;
  const int tx = threadIdx.x & 31, ty = threadIdx.x >> 5;
  #pragma unroll
  for (int rr = 0; rr < 4; ++rr)
    t[ty + rr * 8][tx] = src[(long)(r0 + ty + rr * 8) * C + c0 + tx];
  __syncthreads();
  #pragma unroll
  for (int rr = 0; rr < 4; ++rr)
    dst[(long)(c0 + ty + rr * 8) * 768 + r0 + tx] = f2bf(t[tx][ty + rr * 8]);
}

// ---------------- GEMM1: 256x256 tile, BK=32, ring-4 LDS, counted vmcnt, setprio ----------------
// u@W_in + b_in -> proj bf16 [b][c][l].  8-phase-style schedule (T3+T4+T5):
//  - 4 LDS slots of 32KB (A 256x32 @+0, B 256x32 @+16384); slot = kt&3; prefetch kt+3.
//  - vmcnt(8) once per K-step (leaves the 2 most recent K-steps' 8 loads in flight);
//    tail: vmcnt(4) at kt=21, vmcnt(0) at kt=22. Never a full drain mid-loop.
//  - 2 phases/K-step (M-halves): {ds_read frags | 2 gld_lds -> bar -> prio1 16 MFMA prio0 -> bar}.
//  - 64B LDS row stride => wave b128 frag reads hit the 8-words/bank physical floor (no swizzle needed).
__device__ __forceinline__ void g1_vmwait(int VM) {
  if (VM == 8)      asm volatile("s_waitcnt vmcnt(8)" ::: "memory");
  else if (VM == 4) asm volatile("s_waitcnt vmcnt(4)" ::: "memory");
  else if (VM == 0) asm volatile("s_waitcnt vmcnt(0)" ::: "memory");
}

template<bool STG, int VM>
__device__ __forceinline__ void g1_step(int kt, char* smemc, int tid,
                                        int wm128, int wn64, int fm, int fk8,
                                        const unsigned short* aP, const unsigned short* bP,
                                        f32x4 (&acc)[8][4]) {
  const int s = kt & 3;
  const unsigned short* As = (const unsigned short*)(smemc + s * 32768);
  const unsigned short* Bs = (const unsigned short*)(smemc + s * 32768 + 16384);
  // ---- phase A: M-frags 0..3 ----
  bf16x8 af[4], bfr[4];
  #pragma unroll
  for (int i = 0; i < 4; ++i) af[i]  = *(const bf16x8*)&As[(wm128 + i * 16 + fm) * 32 + fk8];
  #pragma unroll
  for (int jj = 0; jj < 4; ++jj) bfr[jj] = *(const bf16x8*)&Bs[(wn64 + jj * 16 + fm) * 32 + fk8];
  if (STG) {  // stage A halves of kt+3 into slot (kt+3)&3
    const unsigned short* ap = aP + (kt + 3) * 32;
    char* d = smemc + ((kt + 3) & 3) * 32768 + tid * 16;
    gld_lds16(ap,         d);
    gld_lds16(ap + 98304, d + 8192);   // 128*768
  }
  asm volatile("" ::: "memory");
  __builtin_amdgcn_s_barrier();
  __builtin_amdgcn_s_setprio(1);
  __builtin_amdgcn_sched_barrier(0);
  #pragma unroll
  for (int i = 0; i < 4; ++i)
    #pragma unroll
    for (int jj = 0; jj < 4; ++jj)
      acc[i][jj] = __builtin_amdgcn_mfma_f32_16x16x32_bf16(af[i], bfr[jj], acc[i][jj], 0, 0, 0);
  __builtin_amdgcn_sched_barrier(0);
  __builtin_amdgcn_s_setprio(0);
  asm volatile("" ::: "memory");
  __builtin_amdgcn_s_barrier();
  // ---- phase B: M-frags 4..7 (B-frags reused from registers) ----
  bf16x8 ag[4];
  #pragma unroll
  for (int i = 0; i < 4; ++i) ag[i] = *(const bf16x8*)&As[(wm128 + (i + 4) * 16 + fm) * 32 + fk8];
  if (STG) {  // stage B halves of kt+3
    const unsigned short* bp = bP + (kt + 3) * 32;
    char* d = smemc + ((kt + 3) & 3) * 32768 + 16384 + tid * 16;
    gld_lds16(bp,         d);
    gld_lds16(bp + 98304, d + 8192);
  }
  asm volatile("" ::: "memory");
  __builtin_amdgcn_s_barrier();
  __builtin_amdgcn_s_setprio(1);
  __builtin_amdgcn_sched_barrier(0);
  #pragma unroll
  for (int i = 0; i < 4; ++i)
    #pragma unroll
    for (int jj = 0; jj < 4; ++jj)
      acc[i + 4][jj] = __builtin_amdgcn_mfma_f32_16x16x32_bf16(ag[i], bfr[jj], acc[i + 4][jj], 0, 0, 0);
  __builtin_amdgcn_sched_barrier(0);
  __builtin_amdgcn_s_setprio(0);
  g1_vmwait(VM);
  asm volatile("" ::: "memory");
  __builtin_amdgcn_s_barrier();
}

__global__ __launch_bounds__(512, 2) void gemm1_8ph(const unsigned short* __restrict__ A,
                                                    const unsigned short* __restrict__ Bt,
                                                    const float* __restrict__ bias,
                                                    unsigned short* __restrict__ proj) {
  extern __shared__ char smemc[];          // 131072 B dynamic
  const int tid = threadIdx.x;
  const int w = tid >> 6, lane = tid & 63;
  // XCD-aware swizzle: 576 blocks, 576%8==0 (bijective). XCD x owns m-band of 8 tiles, sweeps n.
  const int id = blockIdx.x;
  const int x8 = id & 7, jb = id >> 3;            // jb in [0,72)
  const int mt = x8 * 8 + jb / 9, nt = jb % 9;
  const int m0 = mt * 256, n0 = nt * 256;
  const int wm128 = (w >> 2) * 128, wn64 = (w & 3) * 64;
  const int fm = lane & 15, fk8 = (lane >> 4) * 8;
  const unsigned short* aP = A  + (size_t)(m0 + (tid >> 2)) * 768 + (tid & 3) * 8;
  const unsigned short* bP = Bt + (size_t)(n0 + (tid >> 2)) * 768 + (tid & 3) * 8;
  f32x4 acc[8][4] = {};

  // prologue: stage K-steps 0..2 (slots 0..2), wait slot0 (oldest 4 of 12 issued)
  #pragma unroll
  for (int kt = 0; kt < 3; ++kt) {
    char* d = smemc + kt * 32768 + tid * 16;
    const unsigned short* ap = aP + kt * 32;
    const unsigned short* bp = bP + kt * 32;
    gld_lds16(ap,         d);
    gld_lds16(ap + 98304, d + 8192);
    gld_lds16(bp,         d + 16384);
    gld_lds16(bp + 98304, d + 24576);
  }
  asm volatile("s_waitcnt vmcnt(8)" ::: "memory");
  asm volatile("" ::: "memory");
  __builtin_amdgcn_s_barrier();

  #pragma unroll 1
  for (int kt = 0; kt < 21; ++kt)
    g1_step<true, 8>(kt, smemc, tid, wm128, wn64, fm, fk8, aP, bP, acc);
  g1_step<false, 4>(21, smemc, tid, wm128, wn64, fm, fk8, aP, bP, acc);
  g1_step<false, 0>(22, smemc, tid, wm128, wn64, fm, fk8, aP, bP, acc);
  g1_step<false, -1>(23, smemc, tid, wm128, wn64, fm, fk8, aP, bP, acc);

  // epilogue: direct bf16 stores to proj[b][c][l] (no LDS, no barriers)
  const int b = m0 >> 12, l0 = m0 & 4095;
  const int fk4 = (fk8 >> 3) * 4;
  #pragma unroll
  for (int j2 = 0; j2 < 4; ++j2) {
    int c = n0 + wn64 + j2 * 16 + fm;
    float bb = bias[c];
    unsigned short* pr = proj + ((size_t)b * C3 + c) * L_SEQ + l0 + wm128 + fk4;
    #pragma unroll
    for (int i = 0; i < 8; ++i) {
      f32x4 a = acc[i][j2];
      ushort4 o;
      o.x = f2bf(a[0] + bb); o.y = f2bf(a[1] + bb);
      o.z = f2bf(a[2] + bb); o.w = f2bf(a[3] + bb);
      *(ushort4*)&pr[i * 16] = o;
    }
  }
}

// ---------------- GEMM2 (MFMA, dbuf, 64x128 tile): v2F@W_out + b_out -> out ----------------
#define G2_BUF 12288
__global__ __launch_bounds__(256) void gemm2_mfma(const unsigned short* __restrict__ A,
                                                  const unsigned short* __restrict__ Bt,
                                                  const float* __restrict__ bias,
                                                  float* __restrict__ out) {
  __shared__ __align__(16) char smem[24576];
  const int tid = threadIdx.x;
  const int w = tid >> 6, lane = tid & 63;
  const int lr = tid >> 2, lc = tid & 3;
  const int id = blockIdx.y * 6 + blockIdx.x;   // 1536 blocks
  const int x8 = id & 7, j = id >> 3;           // j in [0,192)
  const int m0 = (x8 * 32 + j / 6) * 64;
  const int n0 = (j % 6) * 128;
  const int wm = (w & 1) * 32, wn = (w >> 1) * 64;
  const int fm = lane & 15, fk = lane >> 4;
  f32x4 acc[2][4] = {};
  const unsigned short* Ag = A + (size_t)(m0 + lr) * 768 + lc * 8;   // 64 rows
  const unsigned short* Bg = Bt + (size_t)(n0 + lr) * 768 + lc * 8;  // 128 rows (two 64-row halves)

  {
    char* dst = smem + tid * 16;
    gld_lds16(Ag,            dst);           // A rows 0..63   -> [0,4096)
    gld_lds16(Bg,            dst + 4096);    // B rows 0..63   -> [4096,8192)
    gld_lds16(Bg + 64 * 768, dst + 8192);    // B rows 64..127 -> [8192,12288)
  }
  for (int kk = 0; kk < 24; ++kk) {
    const int cur = (kk & 1) * G2_BUF;
    __syncthreads();
    if (kk < 23) {
      const int k0 = (kk + 1) * 32;
      char* dst = smem + ((kk + 1) & 1) * G2_BUF + tid * 16;
      gld_lds16(Ag + k0,            dst);
      gld_lds16(Bg + k0,            dst + 4096);
      gld_lds16(Bg + k0 + 64 * 768, dst + 8192);
    }
    const unsigned short* As = (const unsigned short*)(smem + cur);
    const unsigned short* Bs = As + 2048;
    bf16x8 af[2], bfr[4];
    #pragma unroll
    for (int i = 0; i < 2; ++i) af[i]  = *(const bf16x8*)&As[(wm + i * 16 + fm) * 32 + fk * 8];
    #pragma unroll
    for (int j2 = 0; j2 < 4; ++j2) bfr[j2] = *(const bf16x8*)&Bs[(wn + j2 * 16 + fm) * 32 + fk * 8];
    #pragma unroll
    for (int i = 0; i < 2; ++i)
      #pragma unroll
      for (int j2 = 0; j2 < 4; ++j2)
        acc[i][j2] = __builtin_amdgcn_mfma_f32_16x16x32_bf16(af[i], bfr[j2], acc[i][j2], 0, 0, 0);
  }

  float* fbuf = (float*)smem + w * 1088;    // 16 x 68 per wave
  const int nf = lane & 15, mq = lane >> 4;
  float4 bb4 = *(const float4*)&bias[n0 + wn + nf * 4];
  #pragma unroll
  for (int i = 0; i < 2; ++i) {
    __syncthreads();
    #pragma unroll
    for (int cg = 0; cg < 4; ++cg)
      #pragma unroll
      for (int r = 0; r < 4; ++r)
        fbuf[(fk * 4 + r) * 68 + cg * 16 + fm] = acc[i][cg][r];
    __syncthreads();
    #pragma unroll
    for (int pass = 0; pass < 4; ++pass) {
      int m_l = pass * 4 + mq;
      float4 v = *(float4*)&fbuf[m_l * 68 + nf * 4];
      v.x += bb4.x; v.y += bb4.y; v.z += bb4.z; v.w += bb4.w;
      *(float4*)&out[(size_t)(m0 + wm + i * 16 + m_l) * D_DIM + n0 + wn + nf * 4] = v;
    }
  }
}

// ---------------- row kernel: conflict-free column LDS + shfl scan ----------------
__global__ __launch_bounds__(256) void row_kernel(const unsigned short* __restrict__ proj,
                                                  unsigned short* __restrict__ v2T,
                                                  const float* __restrict__ conv_k,
                                                  const float* __restrict__ conv_b,
                                                  const float* __restrict__ g_tab,
                                                  const float* __restrict__ f_bias) {
  __shared__ float buf0[4128];
  __shared__ float buf1[4128];
  __shared__ float sgs[2 * TAPS];
  __shared__ float wsum[4];
  __shared__ float bnd[3][4][2];
  const int tid = threadIdx.x;
  const int lane = tid & 63, w = tid >> 6;
  const int b = blockIdx.x / D_DIM, d = blockIdx.x % D_DIM;
  const int g = tid * 16;

  const unsigned short* rowV  = proj + ((size_t)b * C3 + 2 * D_DIM + d) * L_SEQ;
  const unsigned short* rowX0 = proj + ((size_t)b * C3 + d) * L_SEQ;
  const unsigned short* rowX1 = proj + ((size_t)b * C3 + D_DIM + d) * L_SEQ;

  float v[16], x0[16], x1[16];
  #pragma unroll
  for (int k = 0; k < 4; ++k) {
    ushort4 qv = *(const ushort4*)&rowV[g + k * 4];
    v[k * 4] = bf2f(qv.x); v[k * 4 + 1] = bf2f(qv.y); v[k * 4 + 2] = bf2f(qv.z); v[k * 4 + 3] = bf2f(qv.w);
    ushort4 q0 = *(const ushort4*)&rowX0[g + k * 4];
    x0[k * 4] = bf2f(q0.x); x0[k * 4 + 1] = bf2f(q0.y); x0[k * 4 + 2] = bf2f(q0.z); x0[k * 4 + 3] = bf2f(q0.w);
    ushort4 q1 = *(const ushort4*)&rowX1[g + k * 4];
    x1[k * 4] = bf2f(q1.x); x1[k * 4 + 1] = bf2f(q1.y); x1[k * 4 + 2] = bf2f(q1.z); x1[k * 4 + 3] = bf2f(q1.w);
  }

  if (tid < 32) {
    int ph = (tid & 15) * 258 + (tid >> 4);
    buf0[ph] = 0.f; buf1[ph] = 0.f;
  }
  if (tid < 64) sgs[tid] = g_tab[((size_t)((tid >> 5) * D_DIM + d)) * TAPS + (tid & 31)];
  if (lane == 63) {
    bnd[0][w][0] = v[14];  bnd[0][w][1] = v[15];
    bnd[1][w][0] = x0[14]; bnd[1][w][1] = x0[15];
    bnd[2][w][0] = x1[14]; bnd[2][w][1] = x1[15];
  }
  const int cv = 2 * D_DIM + d, cx0 = d, cx1 = D_DIM + d;
  const float kv0 = conv_k[cv],  kv1 = conv_k[C3 + cv],  kv2 = conv_k[2 * C3 + cv],  bv = conv_b[cv];
  const float ka0 = conv_k[cx0], ka1 = conv_k[C3 + cx0], ka2 = conv_k[2 * C3 + cx0], ba = conv_b[cx0];
  const float kb0 = conv_k[cx1], kb1 = conv_k[C3 + cx1], kb2 = conv_k[2 * C3 + cx1], bb = conv_b[cx1];
  const float fb0 = f_bias[d], fb1 = f_bias[D_DIM + d];
  __syncthreads();                                         // bar1

  float vm1 = __shfl_up(v[15], 1),  vm2 = __shfl_up(v[14], 1);
  float am1 = __shfl_up(x0[15], 1), am2 = __shfl_up(x0[14], 1);
  float bm1 = __shfl_up(x1[15], 1), bm2 = __shfl_up(x1[14], 1);
  if (lane == 0) {
    if (w > 0) {
      vm2 = bnd[0][w-1][0]; vm1 = bnd[0][w-1][1];
      am2 = bnd[1][w-1][0]; am1 = bnd[1][w-1][1];
      bm2 = bnd[2][w-1][0]; bm1 = bnd[2][w-1][1];
    } else {
      vm1 = vm2 = am1 = am2 = bm1 = bm2 = 0.f;
    }
  }
  float r[16];
  r[0] = vm2 * kv0 + vm1 * kv1 + v[0] * kv2 + bv;
  r[1] = vm1 * kv0 + v[0] * kv1 + v[1] * kv2 + bv;
  #pragma unroll
  for (int i = 2; i < 16; ++i) r[i] = v[i-2] * kv0 + v[i-1] * kv1 + v[i] * kv2 + bv;
  {
    float t0 = am2 * ka0 + am1 * ka1 + x0[0] * ka2 + ba;
    float t1 = am1 * ka0 + x0[0] * ka1 + x0[1] * ka2 + ba;
    #pragma unroll
    for (int i = 15; i >= 2; --i) x0[i] = x0[i-2] * ka0 + x0[i-1] * ka1 + x0[i] * ka2 + ba;
    x0[0] = t0; x0[1] = t1;
  }
  {
    float t0 = bm2 * kb0 + bm1 * kb1 + x1[0] * kb2 + bb;
    float t1 = bm1 * kb0 + x1[0] * kb1 + x1[1] * kb2 + bb;
    #pragma unroll
    for (int i = 15; i >= 2; --i) x1[i] = x1[i-2] * kb0 + x1[i-1] * kb1 + x1[i] * kb2 + bb;
    x1[0] = t0; x1[1] = t1;
  }
  #pragma unroll
  for (int i = 0; i < 16; ++i) buf0[i * 258 + tid + 2] = r[i];
  __syncthreads();                                         // bar2

  // ---- order 0 ----
  float h[32];
  #pragma unroll
  for (int j = 0; j < 32; ++j) h[j] = buf0[(j & 15) * 258 + tid + (j >> 4)];
  float p[16], run = 0.f;
  #pragma unroll
  for (int i = 0; i < 16; ++i) { run += r[i]; p[i] = run; }
  float s = run;
  #pragma unroll
  for (int off = 1; off < 64; off <<= 1) {
    float o = __shfl_up(s, off);
    if (lane >= off) s += o;
  }
  if (lane == 63) wsum[w] = s;
  __syncthreads();                                         // bar3
  float woff = 0.f;
  #pragma unroll
  for (int k = 0; k < 4; ++k) if (k < w) woff += wsum[k];
  float excl = woff + s - run;
  float y0[16];
  #pragma unroll
  for (int i = 0; i < 16; ++i) {
    float a = fb0 * (excl + p[i]);
    #pragma unroll
    for (int t = 0; t < TAPS; ++t) {
      float vv = (t <= i) ? r[i - t] : h[32 + i - t];
      a += sgs[t] * vv;
    }
    y0[i] = a * x0[i];
  }
  #pragma unroll
  for (int i = 0; i < 16; ++i) buf1[i * 258 + tid + 2] = y0[i];
  __syncthreads();                                         // bar4

  // ---- order 1 ----
  #pragma unroll
  for (int j = 0; j < 32; ++j) h[j] = buf1[(j & 15) * 258 + tid + (j >> 4)];
  run = 0.f;
  #pragma unroll
  for (int i = 0; i < 16; ++i) { run += y0[i]; p[i] = run; }
  s = run;
  #pragma unroll
  for (int off = 1; off < 64; off <<= 1) {
    float o = __shfl_up(s, off);
    if (lane >= off) s += o;
  }
  if (lane == 63) wsum[w] = s;
  __syncthreads();                                         // bar5
  woff = 0.f;
  #pragma unroll
  for (int k = 0; k < 4; ++k) if (k < w) woff += wsum[k];
  excl = woff + s - run;
  unsigned short yout[16];
  #pragma unroll
  for (int i = 0; i < 16; ++i) {
    float a = fb1 * (excl + p[i]);
    #pragma unroll
    for (int t = 0; t < TAPS; ++t) {
      float vv = (t <= i) ? y0[i - t] : h[32 + i - t];
      a += sgs[TAPS + t] * vv;
    }
    yout[i] = f2bf(a * x1[i]);
  }
  unsigned short* outRow = v2T + ((size_t)b * D_DIM + d) * L_SEQ + g;
  *(ushort4*)&outRow[0]  = *(ushort4*)&yout[0];
  *(ushort4*)&outRow[4]  = *(ushort4*)&yout[4];
  *(ushort4*)&outRow[8]  = *(ushort4*)&yout[8];
  *(ushort4*)&outRow[12] = *(ushort4*)&yout[12];
}

// ---------------- v2 transpose: bf16 [b][d][l] -> bf16 [b*l][d] ----------------
__global__ __launch_bounds__(256) void transpose_v2(const unsigned short* __restrict__ src,
                                                    unsigned short* __restrict__ dst) {
  __shared__ unsigned short t[64][66];
  const int l0 = blockIdx.x * 64, d0 = blockIdx.y * 64, b = blockIdx.z;
  const int tx = threadIdx.x & 31, ty = threadIdx.x >> 5;
  const unsigned short* s = src + ((size_t)b * D_DIM + d0) * L_SEQ + l0;
  #pragma unroll
  for (int r = 0; r < 8; ++r) {
    int dd = ty + r * 8;
    *(ushort2*)&t[dd][tx * 2] = *(const ushort2*)&s[(size_t)dd * L_SEQ + tx * 2];
  }
  __syncthreads();
  unsigned short* q = dst + ((size_t)b * L_SEQ + l0) * D_DIM + d0;
  #pragma unroll
  for (int r = 0; r < 8; ++r) {
    int ll = ty + r * 8;
    ushort2 v; v.x = t[tx * 2][ll]; v.y = t[tx * 2 + 1][ll];
    *(ushort2*)&q[(size_t)ll * D_DIM + tx * 2] = v;
  }
}

extern "C" void kernel_launch(void* const* d_in, const int* in_sizes, int n_in,
                              void* d_out, int out_size, void* d_ws, size_t ws_size,
                              hipStream_t stream) {
  (void)in_sizes; (void)n_in; (void)out_size; (void)ws_size;
  const float* u       = (const float*)d_in[0];
  const float* W_in    = (const float*)d_in[1];
  const float* b_in    = (const float*)d_in[2];
  const float* conv_k  = (const float*)d_in[3];
  const float* conv_b  = (const float*)d_in[4];
  const float* W1      = (const float*)d_in[5];
  const float* b1      = (const float*)d_in[6];
  const float* W2      = (const float*)d_in[7];
  const float* b2      = (const float*)d_in[8];
  const float* f_bias  = (const float*)d_in[9];
  const float* f_decay = (const float*)d_in[10];
  const float* W_out   = (const float*)d_in[11];
  const float* b_out   = (const float*)d_in[12];
  float* out = (float*)d_out;

  unsigned short* proj  = (unsigned short*)d_ws;                 // 4*2304*4096 bf16
  unsigned short* v2T   = proj + (size_t)4 * C3 * L_SEQ;         // 4*768*4096 bf16
  unsigned short* ubf   = v2T + (size_t)4 * D_DIM * L_SEQ;       // 16384*768 bf16
  unsigned short* v2F   = ubf;                                   // alias (dead after gemm1)
  unsigned short* W_inT = ubf + (size_t)16384 * 768;
  unsigned short* W_outT= W_inT + (size_t)C3 * D_DIM;
  float* g_tab          = (float*)(W_outT + (size_t)D_DIM * D_DIM);

  static bool g1_attr = false;
  if (!g1_attr) {
    (void)hipFuncSetAttribute(reinterpret_cast<const void*>(gemm1_8ph),
                              hipFuncAttributeMaxDynamicSharedMemorySize, 131072);
    g1_attr = true;
  }

  filt_kernel<<<192, 256, 0, stream>>>(W1, b1, W2, b2, f_decay, g_tab);
  cvt_kernel<<<12288, 256, 0, stream>>>(u, ubf);
  wtrans_kernel<<<dim3(72, 24, 2), 256, 0, stream>>>(W_in, W_inT, W_out, W_outT);
  gemm1_8ph<<<576, 512, 131072, stream>>>(ubf, W_inT, b_in, proj);
  row_kernel<<<3072, 256, 0, stream>>>(proj, v2T, conv_k, conv_b, g_tab, f_bias);
  transpose_v2<<<dim3(64, 12, 4), 256, 0, stream>>>(v2T, v2F);
  gemm2_mfma<<<dim3(6, 256), 256, 0, stream>>>(v2F, W_outT, b_out, out);
}

// Round 2
// 310.857 us; speedup vs baseline: 1.0479x; 1.0479x over previous
//
#include <hip/hip_runtime.h>
#include <math.h>

#define L_SEQ 4096
#define D_DIM 768
#define C3    2304
#define TAPS  32

typedef __attribute__((ext_vector_type(8))) short bf16x8;
typedef __attribute__((ext_vector_type(4))) float f32x4;

__device__ __forceinline__ unsigned short f2bf(float x) {
  union { float f; unsigned u; } v; v.f = x;
  unsigned r = v.u + 0x7FFF + ((v.u >> 16) & 1);
  return (unsigned short)(r >> 16);
}
__device__ __forceinline__ float bf2f(unsigned short u) {
  union { unsigned u; float f; } v; v.u = ((unsigned)u) << 16; return v.f;
}
__device__ __forceinline__ void gld_lds16(const void* g, void* l) {
  __builtin_amdgcn_global_load_lds((const __attribute__((address_space(1))) void*)g,
                                   (__attribute__((address_space(3))) void*)l, 16, 0, 0);
}

// ---------------- filter: g_tab[c2][t] for t<32 (decay kills lags >=32) ----------------
__global__ __launch_bounds__(256) void filt_kernel(const float* __restrict__ W1,
                                                   const float* __restrict__ b1,
                                                   const float* __restrict__ W2,
                                                   const float* __restrict__ b2,
                                                   const float* __restrict__ f_decay,
                                                   float* __restrict__ g_tab) {
  __shared__ float phi_s[2048];
  const int tid = threadIdx.x;
  #pragma unroll
  for (int it = 0; it < 8; ++it) {
    int idx = tid + it * 256;
    int t = idx >> 6, f = idx & 63;
    float tt = (float)t / 4095.0f;
    float s = b1[f];
    #pragma unroll
    for (int e = 0; e < 33; ++e)
      s += sinf(tt * (float)e * 10.0f) * W1[e * 64 + f];
    phi_s[idx] = sinf(10.0f * s);
  }
  __syncthreads();
  int idx = blockIdx.x * 256 + tid;        // 1536*32
  int c2 = idx >> 5, t = idx & 31;
  float acc = b2[c2];
  #pragma unroll 8
  for (int f = 0; f < 64; ++f)
    acc += phi_s[t * 64 + f] * W2[f * 1536 + c2];
  float r = expf(f_decay[c2]);
  g_tab[idx] = acc * expf(-r * (float)t * (4096.0f / 4095.0f));
}

// ---------------- cvt u: fp32 -> bf16 ----------------
__global__ __launch_bounds__(256) void cvt_kernel(const float* __restrict__ src,
                                                  unsigned short* __restrict__ dst) {
  int idx = (blockIdx.x * 256 + threadIdx.x) * 4;
  float4 v = *(const float4*)&src[idx];
  ushort4 o;
  o.x = f2bf(v.x); o.y = f2bf(v.y); o.z = f2bf(v.z); o.w = f2bf(v.w);
  *(ushort4*)&dst[idx] = o;
}

// ---------------- weight transposes: fp32 [768][C] -> bf16 [C][768] ----------------
__global__ __launch_bounds__(256) void wtrans_kernel(const float* __restrict__ W_in,
                                                     unsigned short* __restrict__ W_inT,
                                                     const float* __restrict__ W_out,
                                                     unsigned short* __restrict__ W_outT) {
  __shared__ float t[32][33];
  const int z = blockIdx.z;
  const float* src = z ? W_out : W_in;
  unsigned short* dst = z ? W_outT : W_inT;
  const int C = z ? 768 : 2304;
  const int c0 = blockIdx.x * 32, r0 = blockIdx.y * 32;
  if (c0 >= C) return;
  const int tx = threadIdx.x & 31, ty = threadIdx.x >> 5;
  #pragma unroll
  for (int rr = 0; rr < 4; ++rr)
    t[ty + rr * 8][tx] = src[(long)(r0 + ty + rr * 8) * C + c0 + tx];
  __syncthreads();
  #pragma unroll
  for (int rr = 0; rr < 4; ++rr)
    dst[(long)(c0 + ty + rr * 8) * 768 + r0 + tx] = f2bf(t[tx][ty + rr * 8]);
}

// ---------------- GEMM1: 256x256 tile, BK=32, ring-4 LDS, counted vmcnt, setprio ----------------
// Chunk swizzle (T2, both-sides): LDS[row][c16] = G[row][c16 ^ ((row>>1)&3)].
//  - stage: linear LDS dest (gld_lds requirement), pre-swizzled GLOBAL source column:
//      thread tid=(row*4+c) loads chunk (tid&3)^((tid>>3)&3).
//  - read: lane (fm, q=lane>>4) reads chunk q^((fm>>1)&3)  -> per-16-lane banks tile
//      all 8 four-bank groups exactly twice = conflict-free floor.
// Schedule: 4 LDS slots of 32KB; prefetch kt+3; vmcnt(8) once per K-step (tail 4, 0);
//  2 phases/K-step (M-halves): {ds_read frags | 2 gld_lds -> bar -> prio1 16 MFMA prio0 -> bar}.
__device__ __forceinline__ void g1_vmwait(int VM) {
  if (VM == 8)      asm volatile("s_waitcnt vmcnt(8)" ::: "memory");
  else if (VM == 4) asm volatile("s_waitcnt vmcnt(4)" ::: "memory");
  else if (VM == 0) asm volatile("s_waitcnt vmcnt(0)" ::: "memory");
}

template<bool STG, int VM>
__device__ __forceinline__ void g1_step(int kt, char* smemc, int tid,
                                        int wm128, int wn64, int fm, int csel,
                                        const unsigned short* aP, const unsigned short* bP,
                                        f32x4 (&acc)[8][4]) {
  const int s = kt & 3;
  const unsigned short* As = (const unsigned short*)(smemc + s * 32768);
  const unsigned short* Bs = (const unsigned short*)(smemc + s * 32768 + 16384);
  // ---- phase A: M-frags 0..3 ----
  bf16x8 af[4], bfr[4];
  #pragma unroll
  for (int i = 0; i < 4; ++i) af[i]  = *(const bf16x8*)&As[(wm128 + i * 16 + fm) * 32 + csel];
  #pragma unroll
  for (int jj = 0; jj < 4; ++jj) bfr[jj] = *(const bf16x8*)&Bs[(wn64 + jj * 16 + fm) * 32 + csel];
  if (STG) {  // stage A halves of kt+3 into slot (kt+3)&3
    const unsigned short* ap = aP + (kt + 3) * 32;
    char* d = smemc + ((kt + 3) & 3) * 32768 + tid * 16;
    gld_lds16(ap,         d);
    gld_lds16(ap + 98304, d + 8192);   // 128*768
  }
  asm volatile("" ::: "memory");
  __builtin_amdgcn_s_barrier();
  __builtin_amdgcn_s_setprio(1);
  __builtin_amdgcn_sched_barrier(0);
  #pragma unroll
  for (int i = 0; i < 4; ++i)
    #pragma unroll
    for (int jj = 0; jj < 4; ++jj)
      acc[i][jj] = __builtin_amdgcn_mfma_f32_16x16x32_bf16(af[i], bfr[jj], acc[i][jj], 0, 0, 0);
  __builtin_amdgcn_sched_barrier(0);
  __builtin_amdgcn_s_setprio(0);
  asm volatile("" ::: "memory");
  __builtin_amdgcn_s_barrier();
  // ---- phase B: M-frags 4..7 (B-frags reused from registers) ----
  bf16x8 ag[4];
  #pragma unroll
  for (int i = 0; i < 4; ++i) ag[i] = *(const bf16x8*)&As[(wm128 + (i + 4) * 16 + fm) * 32 + csel];
  if (STG) {  // stage B halves of kt+3
    const unsigned short* bp = bP + (kt + 3) * 32;
    char* d = smemc + ((kt + 3) & 3) * 32768 + 16384 + tid * 16;
    gld_lds16(bp,         d);
    gld_lds16(bp + 98304, d + 8192);
  }
  asm volatile("" ::: "memory");
  __builtin_amdgcn_s_barrier();
  __builtin_amdgcn_s_setprio(1);
  __builtin_amdgcn_sched_barrier(0);
  #pragma unroll
  for (int i = 0; i < 4; ++i)
    #pragma unroll
    for (int jj = 0; jj < 4; ++jj)
      acc[i + 4][jj] = __builtin_amdgcn_mfma_f32_16x16x32_bf16(ag[i], bfr[jj], acc[i + 4][jj], 0, 0, 0);
  __builtin_amdgcn_sched_barrier(0);
  __builtin_amdgcn_s_setprio(0);
  g1_vmwait(VM);
  asm volatile("" ::: "memory");
  __builtin_amdgcn_s_barrier();
}

__global__ __launch_bounds__(512, 2) void gemm1_8ph(const unsigned short* __restrict__ A,
                                                    const unsigned short* __restrict__ Bt,
                                                    const float* __restrict__ bias,
                                                    unsigned short* __restrict__ proj) {
  extern __shared__ char smemc[];          // 131072 B dynamic
  const int tid = threadIdx.x;
  const int w = tid >> 6, lane = tid & 63;
  // XCD-aware swizzle: 576 blocks, 576%8==0 (bijective). XCD x owns m-band of 8 tiles, sweeps n.
  const int id = blockIdx.x;
  const int x8 = id & 7, jb = id >> 3;            // jb in [0,72)
  const int mt = x8 * 8 + jb / 9, nt = jb % 9;
  const int m0 = mt * 256, n0 = nt * 256;
  const int wm128 = (w >> 2) * 128, wn64 = (w & 3) * 64;
  const int fm = lane & 15;
  const int csel = (((lane >> 4) ^ ((fm >> 1) & 3)) << 3);   // swizzled chunk, element units
  // pre-swizzled global source column for linear-dest gld_lds staging
  const int q_src = ((tid & 3) ^ ((tid >> 3) & 3)) * 8;
  const unsigned short* aP = A  + (size_t)(m0 + (tid >> 2)) * 768 + q_src;
  const unsigned short* bP = Bt + (size_t)(n0 + (tid >> 2)) * 768 + q_src;
  f32x4 acc[8][4] = {};

  // prologue: stage K-steps 0..2 (slots 0..2), wait slot0 (oldest 4 of 12 issued)
  #pragma unroll
  for (int kt = 0; kt < 3; ++kt) {
    char* d = smemc + kt * 32768 + tid * 16;
    const unsigned short* ap = aP + kt * 32;
    const unsigned short* bp = bP + kt * 32;
    gld_lds16(ap,         d);
    gld_lds16(ap + 98304, d + 8192);
    gld_lds16(bp,         d + 16384);
    gld_lds16(bp + 98304, d + 24576);
  }
  asm volatile("s_waitcnt vmcnt(8)" ::: "memory");
  asm volatile("" ::: "memory");
  __builtin_amdgcn_s_barrier();

  #pragma unroll 1
  for (int kt = 0; kt < 21; ++kt)
    g1_step<true, 8>(kt, smemc, tid, wm128, wn64, fm, csel, aP, bP, acc);
  g1_step<false, 4>(21, smemc, tid, wm128, wn64, fm, csel, aP, bP, acc);
  g1_step<false, 0>(22, smemc, tid, wm128, wn64, fm, csel, aP, bP, acc);
  g1_step<false, -1>(23, smemc, tid, wm128, wn64, fm, csel, aP, bP, acc);

  // epilogue: LDS-transpose (16x68-padded, proven pattern) -> coalesced 128B ushort4 runs along l
  const int b = m0 >> 12, l0 = m0 & 4095;
  float* fbuf = (float*)smemc + w * 1088;   // 16 x 68 per wave (34816 B total < 128 KB)
  const int fk = lane >> 4;                 // 0..3
  #pragma unroll
  for (int j2 = 0; j2 < 4; ++j2) {
    #pragma unroll
    for (int ih = 0; ih < 2; ++ih) {
      __syncthreads();
      #pragma unroll
      for (int i = 0; i < 4; ++i)
        *(f32x4*)&fbuf[fm * 68 + i * 16 + fk * 4] = acc[ih * 4 + i][j2];
      __syncthreads();
      #pragma unroll
      for (int p = 0; p < 4; ++p) {
        int nl = p * 4 + fk;
        int c = n0 + wn64 + j2 * 16 + nl;
        float4 v = *(float4*)&fbuf[nl * 68 + fm * 4];
        float bb = bias[c];
        ushort4 o;
        o.x = f2bf(v.x + bb); o.y = f2bf(v.y + bb);
        o.z = f2bf(v.z + bb); o.w = f2bf(v.w + bb);
        *(ushort4*)&proj[((size_t)b * C3 + c) * L_SEQ + l0 + wm128 + ih * 64 + fm * 4] = o;
      }
    }
  }
}

// ---------------- GEMM2 (MFMA, dbuf, 64x128 tile): v2F@W_out + b_out -> out ----------------
#define G2_BUF 12288
__global__ __launch_bounds__(256) void gemm2_mfma(const unsigned short* __restrict__ A,
                                                  const unsigned short* __restrict__ Bt,
                                                  const float* __restrict__ bias,
                                                  float* __restrict__ out) {
  __shared__ __align__(16) char smem[24576];
  const int tid = threadIdx.x;
  const int w = tid >> 6, lane = tid & 63;
  const int lr = tid >> 2, lc = tid & 3;
  const int id = blockIdx.y * 6 + blockIdx.x;   // 1536 blocks
  const int x8 = id & 7, j = id >> 3;           // j in [0,192)
  const int m0 = (x8 * 32 + j / 6) * 64;
  const int n0 = (j % 6) * 128;
  const int wm = (w & 1) * 32, wn = (w >> 1) * 64;
  const int fm = lane & 15, fk = lane >> 4;
  f32x4 acc[2][4] = {};
  const unsigned short* Ag = A + (size_t)(m0 + lr) * 768 + lc * 8;   // 64 rows
  const unsigned short* Bg = Bt + (size_t)(n0 + lr) * 768 + lc * 8;  // 128 rows (two 64-row halves)

  {
    char* dst = smem + tid * 16;
    gld_lds16(Ag,            dst);           // A rows 0..63   -> [0,4096)
    gld_lds16(Bg,            dst + 4096);    // B rows 0..63   -> [4096,8192)
    gld_lds16(Bg + 64 * 768, dst + 8192);    // B rows 64..127 -> [8192,12288)
  }
  for (int kk = 0; kk < 24; ++kk) {
    const int cur = (kk & 1) * G2_BUF;
    __syncthreads();
    if (kk < 23) {
      const int k0 = (kk + 1) * 32;
      char* dst = smem + ((kk + 1) & 1) * G2_BUF + tid * 16;
      gld_lds16(Ag + k0,            dst);
      gld_lds16(Bg + k0,            dst + 4096);
      gld_lds16(Bg + k0 + 64 * 768, dst + 8192);
    }
    const unsigned short* As = (const unsigned short*)(smem + cur);
    const unsigned short* Bs = As + 2048;
    bf16x8 af[2], bfr[4];
    #pragma unroll
    for (int i = 0; i < 2; ++i) af[i]  = *(const bf16x8*)&As[(wm + i * 16 + fm) * 32 + fk * 8];
    #pragma unroll
    for (int j2 = 0; j2 < 4; ++j2) bfr[j2] = *(const bf16x8*)&Bs[(wn + j2 * 16 + fm) * 32 + fk * 8];
    #pragma unroll
    for (int i = 0; i < 2; ++i)
      #pragma unroll
      for (int j2 = 0; j2 < 4; ++j2)
        acc[i][j2] = __builtin_amdgcn_mfma_f32_16x16x32_bf16(af[i], bfr[j2], acc[i][j2], 0, 0, 0);
  }

  float* fbuf = (float*)smem + w * 1088;    // 16 x 68 per wave
  const int nf = lane & 15, mq = lane >> 4;
  float4 bb4 = *(const float4*)&bias[n0 + wn + nf * 4];
  #pragma unroll
  for (int i = 0; i < 2; ++i) {
    __syncthreads();
    #pragma unroll
    for (int cg = 0; cg < 4; ++cg)
      #pragma unroll
      for (int r = 0; r < 4; ++r)
        fbuf[(fk * 4 + r) * 68 + cg * 16 + fm] = acc[i][cg][r];
    __syncthreads();
    #pragma unroll
    for (int pass = 0; pass < 4; ++pass) {
      int m_l = pass * 4 + mq;
      float4 v = *(float4*)&fbuf[m_l * 68 + nf * 4];
      v.x += bb4.x; v.y += bb4.y; v.z += bb4.z; v.w += bb4.w;
      *(float4*)&out[(size_t)(m0 + wm + i * 16 + m_l) * D_DIM + n0 + wn + nf * 4] = v;
    }
  }
}

// ---------------- row kernel: conflict-free column LDS + shfl scan ----------------
__global__ __launch_bounds__(256) void row_kernel(const unsigned short* __restrict__ proj,
                                                  unsigned short* __restrict__ v2T,
                                                  const float* __restrict__ conv_k,
                                                  const float* __restrict__ conv_b,
                                                  const float* __restrict__ g_tab,
                                                  const float* __restrict__ f_bias) {
  __shared__ float buf0[4128];
  __shared__ float buf1[4128];
  __shared__ float sgs[2 * TAPS];
  __shared__ float wsum[4];
  __shared__ float bnd[3][4][2];
  const int tid = threadIdx.x;
  const int lane = tid & 63, w = tid >> 6;
  const int b = blockIdx.x / D_DIM, d = blockIdx.x % D_DIM;
  const int g = tid * 16;

  const unsigned short* rowV  = proj + ((size_t)b * C3 + 2 * D_DIM + d) * L_SEQ;
  const unsigned short* rowX0 = proj + ((size_t)b * C3 + d) * L_SEQ;
  const unsigned short* rowX1 = proj + ((size_t)b * C3 + D_DIM + d) * L_SEQ;

  float v[16], x0[16], x1[16];
  #pragma unroll
  for (int k = 0; k < 4; ++k) {
    ushort4 qv = *(const ushort4*)&rowV[g + k * 4];
    v[k * 4] = bf2f(qv.x); v[k * 4 + 1] = bf2f(qv.y); v[k * 4 + 2] = bf2f(qv.z); v[k * 4 + 3] = bf2f(qv.w);
    ushort4 q0 = *(const ushort4*)&rowX0[g + k * 4];
    x0[k * 4] = bf2f(q0.x); x0[k * 4 + 1] = bf2f(q0.y); x0[k * 4 + 2] = bf2f(q0.z); x0[k * 4 + 3] = bf2f(q0.w);
    ushort4 q1 = *(const ushort4*)&rowX1[g + k * 4];
    x1[k * 4] = bf2f(q1.x); x1[k * 4 + 1] = bf2f(q1.y); x1[k * 4 + 2] = bf2f(q1.z); x1[k * 4 + 3] = bf2f(q1.w);
  }

  if (tid < 32) {
    int ph = (tid & 15) * 258 + (tid >> 4);
    buf0[ph] = 0.f; buf1[ph] = 0.f;
  }
  if (tid < 64) sgs[tid] = g_tab[((size_t)((tid >> 5) * D_DIM + d)) * TAPS + (tid & 31)];
  if (lane == 63) {
    bnd[0][w][0] = v[14];  bnd[0][w][1] = v[15];
    bnd[1][w][0] = x0[14]; bnd[1][w][1] = x0[15];
    bnd[2][w][0] = x1[14]; bnd[2][w][1] = x1[15];
  }
  const int cv = 2 * D_DIM + d, cx0 = d, cx1 = D_DIM + d;
  const float kv0 = conv_k[cv],  kv1 = conv_k[C3 + cv],  kv2 = conv_k[2 * C3 + cv],  bv = conv_b[cv];
  const float ka0 = conv_k[cx0], ka1 = conv_k[C3 + cx0], ka2 = conv_k[2 * C3 + cx0], ba = conv_b[cx0];
  const float kb0 = conv_k[cx1], kb1 = conv_k[C3 + cx1], kb2 = conv_k[2 * C3 + cx1], bb = conv_b[cx1];
  const float fb0 = f_bias[d], fb1 = f_bias[D_DIM + d];
  __syncthreads();                                         // bar1

  float vm1 = __shfl_up(v[15], 1),  vm2 = __shfl_up(v[14], 1);
  float am1 = __shfl_up(x0[15], 1), am2 = __shfl_up(x0[14], 1);
  float bm1 = __shfl_up(x1[15], 1), bm2 = __shfl_up(x1[14], 1);
  if (lane == 0) {
    if (w > 0) {
      vm2 = bnd[0][w-1][0]; vm1 = bnd[0][w-1][1];
      am2 = bnd[1][w-1][0]; am1 = bnd[1][w-1][1];
      bm2 = bnd[2][w-1][0]; bm1 = bnd[2][w-1][1];
    } else {
      vm1 = vm2 = am1 = am2 = bm1 = bm2 = 0.f;
    }
  }
  float r[16];
  r[0] = vm2 * kv0 + vm1 * kv1 + v[0] * kv2 + bv;
  r[1] = vm1 * kv0 + v[0] * kv1 + v[1] * kv2 + bv;
  #pragma unroll
  for (int i = 2; i < 16; ++i) r[i] = v[i-2] * kv0 + v[i-1] * kv1 + v[i] * kv2 + bv;
  {
    float t0 = am2 * ka0 + am1 * ka1 + x0[0] * ka2 + ba;
    float t1 = am1 * ka0 + x0[0] * ka1 + x0[1] * ka2 + ba;
    #pragma unroll
    for (int i = 15; i >= 2; --i) x0[i] = x0[i-2] * ka0 + x0[i-1] * ka1 + x0[i] * ka2 + ba;
    x0[0] = t0; x0[1] = t1;
  }
  {
    float t0 = bm2 * kb0 + bm1 * kb1 + x1[0] * kb2 + bb;
    float t1 = bm1 * kb0 + x1[0] * kb1 + x1[1] * kb2 + bb;
    #pragma unroll
    for (int i = 15; i >= 2; --i) x1[i] = x1[i-2] * kb0 + x1[i-1] * kb1 + x1[i] * kb2 + bb;
    x1[0] = t0; x1[1] = t1;
  }
  #pragma unroll
  for (int i = 0; i < 16; ++i) buf0[i * 258 + tid + 2] = r[i];
  __syncthreads();                                         // bar2

  // ---- order 0 ----
  float h[32];
  #pragma unroll
  for (int j = 0; j < 32; ++j) h[j] = buf0[(j & 15) * 258 + tid + (j >> 4)];
  float p[16], run = 0.f;
  #pragma unroll
  for (int i = 0; i < 16; ++i) { run += r[i]; p[i] = run; }
  float s = run;
  #pragma unroll
  for (int off = 1; off < 64; off <<= 1) {
    float o = __shfl_up(s, off);
    if (lane >= off) s += o;
  }
  if (lane == 63) wsum[w] = s;
  __syncthreads();                                         // bar3
  float woff = 0.f;
  #pragma unroll
  for (int k = 0; k < 4; ++k) if (k < w) woff += wsum[k];
  float excl = woff + s - run;
  float y0[16];
  #pragma unroll
  for (int i = 0; i < 16; ++i) {
    float a = fb0 * (excl + p[i]);
    #pragma unroll
    for (int t = 0; t < TAPS; ++t) {
      float vv = (t <= i) ? r[i - t] : h[32 + i - t];
      a += sgs[t] * vv;
    }
    y0[i] = a * x0[i];
  }
  #pragma unroll
  for (int i = 0; i < 16; ++i) buf1[i * 258 + tid + 2] = y0[i];
  __syncthreads();                                         // bar4

  // ---- order 1 ----
  #pragma unroll
  for (int j = 0; j < 32; ++j) h[j] = buf1[(j & 15) * 258 + tid + (j >> 4)];
  run = 0.f;
  #pragma unroll
  for (int i = 0; i < 16; ++i) { run += y0[i]; p[i] = run; }
  s = run;
  #pragma unroll
  for (int off = 1; off < 64; off <<= 1) {
    float o = __shfl_up(s, off);
    if (lane >= off) s += o;
  }
  if (lane == 63) wsum[w] = s;
  __syncthreads();                                         // bar5
  woff = 0.f;
  #pragma unroll
  for (int k = 0; k < 4; ++k) if (k < w) woff += wsum[k];
  excl = woff + s - run;
  unsigned short yout[16];
  #pragma unroll
  for (int i = 0; i < 16; ++i) {
    float a = fb1 * (excl + p[i]);
    #pragma unroll
    for (int t = 0; t < TAPS; ++t) {
      float vv = (t <= i) ? y0[i - t] : h[32 + i - t];
      a += sgs[TAPS + t] * vv;
    }
    yout[i] = f2bf(a * x1[i]);
  }
  unsigned short* outRow = v2T + ((size_t)b * D_DIM + d) * L_SEQ + g;
  *(ushort4*)&outRow[0]  = *(ushort4*)&yout[0];
  *(ushort4*)&outRow[4]  = *(ushort4*)&yout[4];
  *(ushort4*)&outRow[8]  = *(ushort4*)&yout[8];
  *(ushort4*)&outRow[12] = *(ushort4*)&yout[12];
}

// ---------------- v2 transpose: bf16 [b][d][l] -> bf16 [b*l][d] ----------------
__global__ __launch_bounds__(256) void transpose_v2(const unsigned short* __restrict__ src,
                                                    unsigned short* __restrict__ dst) {
  __shared__ unsigned short t[64][66];
  const int l0 = blockIdx.x * 64, d0 = blockIdx.y * 64, b = blockIdx.z;
  const int tx = threadIdx.x & 31, ty = threadIdx.x >> 5;
  const unsigned short* s = src + ((size_t)b * D_DIM + d0) * L_SEQ + l0;
  #pragma unroll
  for (int r = 0; r < 8; ++r) {
    int dd = ty + r * 8;
    *(ushort2*)&t[dd][tx * 2] = *(const ushort2*)&s[(size_t)dd * L_SEQ + tx * 2];
  }
  __syncthreads();
  unsigned short* q = dst + ((size_t)b * L_SEQ + l0) * D_DIM + d0;
  #pragma unroll
  for (int r = 0; r < 8; ++r) {
    int ll = ty + r * 8;
    ushort2 v; v.x = t[tx * 2][ll]; v.y = t[tx * 2 + 1][ll];
    *(ushort2*)&q[(size_t)ll * D_DIM + tx * 2] = v;
  }
}

extern "C" void kernel_launch(void* const* d_in, const int* in_sizes, int n_in,
                              void* d_out, int out_size, void* d_ws, size_t ws_size,
                              hipStream_t stream) {
  (void)in_sizes; (void)n_in; (void)out_size; (void)ws_size;
  const float* u       = (const float*)d_in[0];
  const float* W_in    = (const float*)d_in[1];
  const float* b_in    = (const float*)d_in[2];
  const float* conv_k  = (const float*)d_in[3];
  const float* conv_b  = (const float*)d_in[4];
  const float* W1      = (const float*)d_in[5];
  const float* b1      = (const float*)d_in[6];
  const float* W2      = (const float*)d_in[7];
  const float* b2      = (const float*)d_in[8];
  const float* f_bias  = (const float*)d_in[9];
  const float* f_decay = (const float*)d_in[10];
  const float* W_out   = (const float*)d_in[11];
  const float* b_out   = (const float*)d_in[12];
  float* out = (float*)d_out;

  unsigned short* proj  = (unsigned short*)d_ws;                 // 4*2304*4096 bf16
  unsigned short* v2T   = proj + (size_t)4 * C3 * L_SEQ;         // 4*768*4096 bf16
  unsigned short* ubf   = v2T + (size_t)4 * D_DIM * L_SEQ;       // 16384*768 bf16
  unsigned short* v2F   = ubf;                                   // alias (dead after gemm1)
  unsigned short* W_inT = ubf + (size_t)16384 * 768;
  unsigned short* W_outT= W_inT + (size_t)C3 * D_DIM;
  float* g_tab          = (float*)(W_outT + (size_t)D_DIM * D_DIM);

  static bool g1_attr = false;
  if (!g1_attr) {
    (void)hipFuncSetAttribute(reinterpret_cast<const void*>(gemm1_8ph),
                              hipFuncAttributeMaxDynamicSharedMemorySize, 131072);
    g1_attr = true;
  }

  filt_kernel<<<192, 256, 0, stream>>>(W1, b1, W2, b2, f_decay, g_tab);
  cvt_kernel<<<12288, 256, 0, stream>>>(u, ubf);
  wtrans_kernel<<<dim3(72, 24, 2), 256, 0, stream>>>(W_in, W_inT, W_out, W_outT);
  gemm1_8ph<<<576, 512, 131072, stream>>>(ubf, W_inT, b_in, proj);
  row_kernel<<<3072, 256, 0, stream>>>(proj, v2T, conv_k, conv_b, g_tab, f_bias);
  transpose_v2<<<dim3(64, 12, 4), 256, 0, stream>>>(v2T, v2F);
  gemm2_mfma<<<dim3(6, 256), 256, 0, stream>>>(v2F, W_outT, b_out, out);
}

// Round 3
// 307.735 us; speedup vs baseline: 1.0586x; 1.0101x over previous
//
#include <hip/hip_runtime.h>
#include <math.h>

#define L_SEQ 4096
#define D_DIM 768
#define C3    2304
#define TAPS  32

typedef __attribute__((ext_vector_type(8))) short bf16x8;
typedef __attribute__((ext_vector_type(4))) float f32x4;

__device__ __forceinline__ unsigned short f2bf(float x) {
  union { float f; unsigned u; } v; v.f = x;
  unsigned r = v.u + 0x7FFF + ((v.u >> 16) & 1);
  return (unsigned short)(r >> 16);
}
__device__ __forceinline__ float bf2f(unsigned short u) {
  union { unsigned u; float f; } v; v.u = ((unsigned)u) << 16; return v.f;
}
__device__ __forceinline__ void gld_lds16(const void* g, void* l) {
  __builtin_amdgcn_global_load_lds((const __attribute__((address_space(1))) void*)g,
                                   (__attribute__((address_space(3))) void*)l, 16, 0, 0);
}

// ---------------- filter: g_tab[c2][t] for t<32 (decay kills lags >=32) ----------------
__global__ __launch_bounds__(256) void filt_kernel(const float* __restrict__ W1,
                                                   const float* __restrict__ b1,
                                                   const float* __restrict__ W2,
                                                   const float* __restrict__ b2,
                                                   const float* __restrict__ f_decay,
                                                   float* __restrict__ g_tab) {
  __shared__ float phi_s[2048];
  const int tid = threadIdx.x;
  #pragma unroll
  for (int it = 0; it < 8; ++it) {
    int idx = tid + it * 256;
    int t = idx >> 6, f = idx & 63;
    float tt = (float)t / 4095.0f;
    float s = b1[f];
    #pragma unroll
    for (int e = 0; e < 33; ++e)
      s += sinf(tt * (float)e * 10.0f) * W1[e * 64 + f];
    phi_s[idx] = sinf(10.0f * s);
  }
  __syncthreads();
  int idx = blockIdx.x * 256 + tid;        // 1536*32
  int c2 = idx >> 5, t = idx & 31;
  float acc = b2[c2];
  #pragma unroll 8
  for (int f = 0; f < 64; ++f)
    acc += phi_s[t * 64 + f] * W2[f * 1536 + c2];
  float r = expf(f_decay[c2]);
  g_tab[idx] = acc * expf(-r * (float)t * (4096.0f / 4095.0f));
}

// ---------------- cvt u: fp32 -> bf16 ----------------
__global__ __launch_bounds__(256) void cvt_kernel(const float* __restrict__ src,
                                                  unsigned short* __restrict__ dst) {
  int idx = (blockIdx.x * 256 + threadIdx.x) * 4;
  float4 v = *(const float4*)&src[idx];
  ushort4 o;
  o.x = f2bf(v.x); o.y = f2bf(v.y); o.z = f2bf(v.z); o.w = f2bf(v.w);
  *(ushort4*)&dst[idx] = o;
}

// ---------------- weight transposes: fp32 [768][C] -> bf16 [C][768] ----------------
__global__ __launch_bounds__(256) void wtrans_kernel(const float* __restrict__ W_in,
                                                     unsigned short* __restrict__ W_inT,
                                                     const float* __restrict__ W_out,
                                                     unsigned short* __restrict__ W_outT) {
  __shared__ float t[32][33];
  const int z = blockIdx.z;
  const float* src = z ? W_out : W_in;
  unsigned short* dst = z ? W_outT : W_inT;
  const int C = z ? 768 : 2304;
  const int c0 = blockIdx.x * 32, r0 = blockIdx.y * 32;
  if (c0 >= C) return;
  const int tx = threadIdx.x & 31, ty = threadIdx.x >> 5;
  #pragma unroll
  for (int rr = 0; rr < 4; ++rr)
    t[ty + rr * 8][tx] = src[(long)(r0 + ty + rr * 8) * C + c0 + tx];
  __syncthreads();
  #pragma unroll
  for (int rr = 0; rr < 4; ++rr)
    dst[(long)(c0 + ty + rr * 8) * 768 + r0 + tx] = f2bf(t[tx][ty + rr * 8]);
}

// ---------------- GEMM1: 256x128 tile, BK=32, ring-3 LDS (72KB -> 2 blocks/CU) ----------------
// Keeps the verified T2 chunk swizzle (r2: conflicts 5.3M->0.59M) and T4 counted vmcnt.
// Structure change vs r2: 2 blocks/CU co-residency does the latency hiding (the r1/r2
// 1-block/CU config exposed every vmcnt/barrier stall to the whole CU).
//  - ring-3 slots of 24 KB: A [256][32] @+0, B [128][32] @+16384; prefetch kt+2.
//  - 3 gld_lds calls/K-step; steady-state s_waitcnt vmcnt(3) (retire kt+1, leave kt+2).
//  - one phase per K-step: {8 ds_read frags | 3 gld_lds -> bar -> prio1 16 MFMA prio0
//      -> vmcnt(3) -> bar}. 2 barriers/K-step.
//  - swizzle: LDS[row][c16] = G[row][c16 ^ ((row>>1)&3)], both-sides (stage src col
//      pre-swizzled, read csel swizzled) -> conflict-free floor.
__device__ __forceinline__ void g1_vmwait(int VM) {
  if (VM == 3)      asm volatile("s_waitcnt vmcnt(3)" ::: "memory");
  else if (VM == 0) asm volatile("s_waitcnt vmcnt(0)" ::: "memory");
}

template<bool STG, int VM>
__device__ __forceinline__ void g1_step(int scur, int sstg, int kt, char* smemc, int tid,
                                        int wmRow, int wn64, int fm, int csel,
                                        const unsigned short* aP, const unsigned short* bP,
                                        f32x4 (&acc)[4][4]) {
  const unsigned short* As = (const unsigned short*)(smemc + scur * 24576);
  const unsigned short* Bs = (const unsigned short*)(smemc + scur * 24576 + 16384);
  bf16x8 af[4], bfr[4];
  #pragma unroll
  for (int i = 0; i < 4; ++i) af[i]  = *(const bf16x8*)&As[(wmRow + i * 16 + fm) * 32 + csel];
  #pragma unroll
  for (int jj = 0; jj < 4; ++jj) bfr[jj] = *(const bf16x8*)&Bs[(wn64 + jj * 16 + fm) * 32 + csel];
  if (STG) {  // stage K-step kt+2 into slot sstg
    const unsigned short* ap = aP + (kt + 2) * 32;
    const unsigned short* bp = bP + (kt + 2) * 32;
    char* d = smemc + sstg * 24576 + tid * 16;
    gld_lds16(ap,         d);
    gld_lds16(ap + 98304, d + 8192);   // A rows 128..255 (128*768)
    gld_lds16(bp,         d + 16384);  // B rows 0..127
  }
  asm volatile("" ::: "memory");
  __builtin_amdgcn_s_barrier();
  __builtin_amdgcn_s_setprio(1);
  __builtin_amdgcn_sched_barrier(0);
  #pragma unroll
  for (int i = 0; i < 4; ++i)
    #pragma unroll
    for (int jj = 0; jj < 4; ++jj)
      acc[i][jj] = __builtin_amdgcn_mfma_f32_16x16x32_bf16(af[i], bfr[jj], acc[i][jj], 0, 0, 0);
  __builtin_amdgcn_sched_barrier(0);
  __builtin_amdgcn_s_setprio(0);
  g1_vmwait(VM);
  asm volatile("" ::: "memory");
  __builtin_amdgcn_s_barrier();
}

__global__ __launch_bounds__(512, 4) void gemm1_2ph(const unsigned short* __restrict__ A,
                                                    const unsigned short* __restrict__ Bt,
                                                    const float* __restrict__ bias,
                                                    unsigned short* __restrict__ proj) {
  extern __shared__ char smemc[];          // 73728 B dynamic (3 x 24576)
  const int tid = threadIdx.x;
  const int w = tid >> 6, lane = tid & 63;
  // XCD swizzle: 1152 blocks (64 m-tiles x 18 n-tiles), 1152%8==0 bijective.
  // XCD x owns m-band [x*8, x*8+8), sweeps n with A-band (~3.1 MB) L2-hot.
  const int id = blockIdx.x;
  const int x8 = id & 7, jb = id >> 3;            // jb in [0,144)
  const int mt = x8 * 8 + jb / 18, nt = jb % 18;
  const int m0 = mt * 256, n0 = nt * 128;
  const int wmRow = (w & 3) * 64, wn64 = (w >> 2) * 64;
  const int fm = lane & 15;
  const int csel = (((lane >> 4) ^ ((fm >> 1) & 3)) << 3);   // swizzled chunk, element units
  const int q_src = ((tid & 3) ^ ((tid >> 3) & 3)) * 8;      // pre-swizzled global col
  const unsigned short* aP = A  + (size_t)(m0 + (tid >> 2)) * 768 + q_src;
  const unsigned short* bP = Bt + (size_t)(n0 + (tid >> 2)) * 768 + q_src;  // tid>>2 < 128 rows
  f32x4 acc[4][4] = {};

  // prologue: stage K-steps 0,1 into slots 0,1; retire slot0's 3 (leave slot1's 3 in flight)
  #pragma unroll
  for (int kt = 0; kt < 2; ++kt) {
    char* d = smemc + kt * 24576 + tid * 16;
    const unsigned short* ap = aP + kt * 32;
    const unsigned short* bp = bP + kt * 32;
    gld_lds16(ap,         d);
    gld_lds16(ap + 98304, d + 8192);
    gld_lds16(bp,         d + 16384);
  }
  asm volatile("s_waitcnt vmcnt(3)" ::: "memory");
  asm volatile("" ::: "memory");
  __builtin_amdgcn_s_barrier();

  int scur = 0;
  #pragma unroll 1
  for (int kt = 0; kt < 22; ++kt) {
    int sstg = scur + 2; if (sstg >= 3) sstg -= 3;
    g1_step<true, 3>(scur, sstg, kt, smemc, tid, wmRow, wn64, fm, csel, aP, bP, acc);
    scur = (scur == 2) ? 0 : scur + 1;
  }
  {
    int sstg = scur + 2; if (sstg >= 3) sstg -= 3;
    g1_step<false, 0>(scur, sstg, 22, smemc, tid, wmRow, wn64, fm, csel, aP, bP, acc);
    scur = (scur == 2) ? 0 : scur + 1;
  }
  g1_step<false, -1>(scur, 0, 23, smemc, tid, wmRow, wn64, fm, csel, aP, bP, acc);

  // epilogue: LDS-transpose (16x68-padded, r2-verified) -> coalesced 128B ushort4 runs along l
  const int b = m0 >> 12, l0 = m0 & 4095;
  float* fbuf = (float*)smemc + w * 1088;   // 16 x 68 per wave (34816 B < 72 KB)
  const int fk = lane >> 4;                 // 0..3
  #pragma unroll
  for (int j2 = 0; j2 < 4; ++j2) {
    __syncthreads();
    #pragma unroll
    for (int i = 0; i < 4; ++i)
      *(f32x4*)&fbuf[fm * 68 + i * 16 + fk * 4] = acc[i][j2];
    __syncthreads();
    #pragma unroll
    for (int p = 0; p < 4; ++p) {
      int nl = p * 4 + fk;
      int c = n0 + wn64 + j2 * 16 + nl;
      float4 v = *(float4*)&fbuf[nl * 68 + fm * 4];
      float bb = bias[c];
      ushort4 o;
      o.x = f2bf(v.x + bb); o.y = f2bf(v.y + bb);
      o.z = f2bf(v.z + bb); o.w = f2bf(v.w + bb);
      *(ushort4*)&proj[((size_t)b * C3 + c) * L_SEQ + l0 + wmRow + fm * 4] = o;
    }
  }
}

// ---------------- GEMM2 (MFMA, dbuf, 64x128 tile): v2F@W_out + b_out -> out ----------------
#define G2_BUF 12288
__global__ __launch_bounds__(256) void gemm2_mfma(const unsigned short* __restrict__ A,
                                                  const unsigned short* __restrict__ Bt,
                                                  const float* __restrict__ bias,
                                                  float* __restrict__ out) {
  __shared__ __align__(16) char smem[24576];
  const int tid = threadIdx.x;
  const int w = tid >> 6, lane = tid & 63;
  const int lr = tid >> 2, lc = tid & 3;
  const int id = blockIdx.y * 6 + blockIdx.x;   // 1536 blocks
  const int x8 = id & 7, j = id >> 3;           // j in [0,192)
  const int m0 = (x8 * 32 + j / 6) * 64;
  const int n0 = (j % 6) * 128;
  const int wm = (w & 1) * 32, wn = (w >> 1) * 64;
  const int fm = lane & 15, fk = lane >> 4;
  f32x4 acc[2][4] = {};
  const unsigned short* Ag = A + (size_t)(m0 + lr) * 768 + lc * 8;   // 64 rows
  const unsigned short* Bg = Bt + (size_t)(n0 + lr) * 768 + lc * 8;  // 128 rows (two 64-row halves)

  {
    char* dst = smem + tid * 16;
    gld_lds16(Ag,            dst);           // A rows 0..63   -> [0,4096)
    gld_lds16(Bg,            dst + 4096);    // B rows 0..63   -> [4096,8192)
    gld_lds16(Bg + 64 * 768, dst + 8192);    // B rows 64..127 -> [8192,12288)
  }
  for (int kk = 0; kk < 24; ++kk) {
    const int cur = (kk & 1) * G2_BUF;
    __syncthreads();
    if (kk < 23) {
      const int k0 = (kk + 1) * 32;
      char* dst = smem + ((kk + 1) & 1) * G2_BUF + tid * 16;
      gld_lds16(Ag + k0,            dst);
      gld_lds16(Bg + k0,            dst + 4096);
      gld_lds16(Bg + k0 + 64 * 768, dst + 8192);
    }
    const unsigned short* As = (const unsigned short*)(smem + cur);
    const unsigned short* Bs = As + 2048;
    bf16x8 af[2], bfr[4];
    #pragma unroll
    for (int i = 0; i < 2; ++i) af[i]  = *(const bf16x8*)&As[(wm + i * 16 + fm) * 32 + fk * 8];
    #pragma unroll
    for (int j2 = 0; j2 < 4; ++j2) bfr[j2] = *(const bf16x8*)&Bs[(wn + j2 * 16 + fm) * 32 + fk * 8];
    #pragma unroll
    for (int i = 0; i < 2; ++i)
      #pragma unroll
      for (int j2 = 0; j2 < 4; ++j2)
        acc[i][j2] = __builtin_amdgcn_mfma_f32_16x16x32_bf16(af[i], bfr[j2], acc[i][j2], 0, 0, 0);
  }

  float* fbuf = (float*)smem + w * 1088;    // 16 x 68 per wave
  const int nf = lane & 15, mq = lane >> 4;
  float4 bb4 = *(const float4*)&bias[n0 + wn + nf * 4];
  #pragma unroll
  for (int i = 0; i < 2; ++i) {
    __syncthreads();
    #pragma unroll
    for (int cg = 0; cg < 4; ++cg)
      #pragma unroll
      for (int r = 0; r < 4; ++r)
        fbuf[(fk * 4 + r) * 68 + cg * 16 + fm] = acc[i][cg][r];
    __syncthreads();
    #pragma unroll
    for (int pass = 0; pass < 4; ++pass) {
      int m_l = pass * 4 + mq;
      float4 v = *(float4*)&fbuf[m_l * 68 + nf * 4];
      v.x += bb4.x; v.y += bb4.y; v.z += bb4.z; v.w += bb4.w;
      *(float4*)&out[(size_t)(m0 + wm + i * 16 + m_l) * D_DIM + n0 + wn + nf * 4] = v;
    }
  }
}

// ---------------- row kernel: conflict-free column LDS + shfl scan ----------------
__global__ __launch_bounds__(256) void row_kernel(const unsigned short* __restrict__ proj,
                                                  unsigned short* __restrict__ v2T,
                                                  const float* __restrict__ conv_k,
                                                  const float* __restrict__ conv_b,
                                                  const float* __restrict__ g_tab,
                                                  const float* __restrict__ f_bias) {
  __shared__ float buf0[4128];
  __shared__ float buf1[4128];
  __shared__ float sgs[2 * TAPS];
  __shared__ float wsum[4];
  __shared__ float bnd[3][4][2];
  const int tid = threadIdx.x;
  const int lane = tid & 63, w = tid >> 6;
  const int b = blockIdx.x / D_DIM, d = blockIdx.x % D_DIM;
  const int g = tid * 16;

  const unsigned short* rowV  = proj + ((size_t)b * C3 + 2 * D_DIM + d) * L_SEQ;
  const unsigned short* rowX0 = proj + ((size_t)b * C3 + d) * L_SEQ;
  const unsigned short* rowX1 = proj + ((size_t)b * C3 + D_DIM + d) * L_SEQ;

  float v[16], x0[16], x1[16];
  #pragma unroll
  for (int k = 0; k < 4; ++k) {
    ushort4 qv = *(const ushort4*)&rowV[g + k * 4];
    v[k * 4] = bf2f(qv.x); v[k * 4 + 1] = bf2f(qv.y); v[k * 4 + 2] = bf2f(qv.z); v[k * 4 + 3] = bf2f(qv.w);
    ushort4 q0 = *(const ushort4*)&rowX0[g + k * 4];
    x0[k * 4] = bf2f(q0.x); x0[k * 4 + 1] = bf2f(q0.y); x0[k * 4 + 2] = bf2f(q0.z); x0[k * 4 + 3] = bf2f(q0.w);
    ushort4 q1 = *(const ushort4*)&rowX1[g + k * 4];
    x1[k * 4] = bf2f(q1.x); x1[k * 4 + 1] = bf2f(q1.y); x1[k * 4 + 2] = bf2f(q1.z); x1[k * 4 + 3] = bf2f(q1.w);
  }

  if (tid < 32) {
    int ph = (tid & 15) * 258 + (tid >> 4);
    buf0[ph] = 0.f; buf1[ph] = 0.f;
  }
  if (tid < 64) sgs[tid] = g_tab[((size_t)((tid >> 5) * D_DIM + d)) * TAPS + (tid & 31)];
  if (lane == 63) {
    bnd[0][w][0] = v[14];  bnd[0][w][1] = v[15];
    bnd[1][w][0] = x0[14]; bnd[1][w][1] = x0[15];
    bnd[2][w][0] = x1[14]; bnd[2][w][1] = x1[15];
  }
  const int cv = 2 * D_DIM + d, cx0 = d, cx1 = D_DIM + d;
  const float kv0 = conv_k[cv],  kv1 = conv_k[C3 + cv],  kv2 = conv_k[2 * C3 + cv],  bv = conv_b[cv];
  const float ka0 = conv_k[cx0], ka1 = conv_k[C3 + cx0], ka2 = conv_k[2 * C3 + cx0], ba = conv_b[cx0];
  const float kb0 = conv_k[cx1], kb1 = conv_k[C3 + cx1], kb2 = conv_k[2 * C3 + cx1], bb = conv_b[cx1];
  const float fb0 = f_bias[d], fb1 = f_bias[D_DIM + d];
  __syncthreads();                                         // bar1

  float vm1 = __shfl_up(v[15], 1),  vm2 = __shfl_up(v[14], 1);
  float am1 = __shfl_up(x0[15], 1), am2 = __shfl_up(x0[14], 1);
  float bm1 = __shfl_up(x1[15], 1), bm2 = __shfl_up(x1[14], 1);
  if (lane == 0) {
    if (w > 0) {
      vm2 = bnd[0][w-1][0]; vm1 = bnd[0][w-1][1];
      am2 = bnd[1][w-1][0]; am1 = bnd[1][w-1][1];
      bm2 = bnd[2][w-1][0]; bm1 = bnd[2][w-1][1];
    } else {
      vm1 = vm2 = am1 = am2 = bm1 = bm2 = 0.f;
    }
  }
  float r[16];
  r[0] = vm2 * kv0 + vm1 * kv1 + v[0] * kv2 + bv;
  r[1] = vm1 * kv0 + v[0] * kv1 + v[1] * kv2 + bv;
  #pragma unroll
  for (int i = 2; i < 16; ++i) r[i] = v[i-2] * kv0 + v[i-1] * kv1 + v[i] * kv2 + bv;
  {
    float t0 = am2 * ka0 + am1 * ka1 + x0[0] * ka2 + ba;
    float t1 = am1 * ka0 + x0[0] * ka1 + x0[1] * ka2 + ba;
    #pragma unroll
    for (int i = 15; i >= 2; --i) x0[i] = x0[i-2] * ka0 + x0[i-1] * ka1 + x0[i] * ka2 + ba;
    x0[0] = t0; x0[1] = t1;
  }
  {
    float t0 = bm2 * kb0 + bm1 * kb1 + x1[0] * kb2 + bb;
    float t1 = bm1 * kb0 + x1[0] * kb1 + x1[1] * kb2 + bb;
    #pragma unroll
    for (int i = 15; i >= 2; --i) x1[i] = x1[i-2] * kb0 + x1[i-1] * kb1 + x1[i] * kb2 + bb;
    x1[0] = t0; x1[1] = t1;
  }
  #pragma unroll
  for (int i = 0; i < 16; ++i) buf0[i * 258 + tid + 2] = r[i];
  __syncthreads();                                         // bar2

  // ---- order 0 ----
  float h[32];
  #pragma unroll
  for (int j = 0; j < 32; ++j) h[j] = buf0[(j & 15) * 258 + tid + (j >> 4)];
  float p[16], run = 0.f;
  #pragma unroll
  for (int i = 0; i < 16; ++i) { run += r[i]; p[i] = run; }
  float s = run;
  #pragma unroll
  for (int off = 1; off < 64; off <<= 1) {
    float o = __shfl_up(s, off);
    if (lane >= off) s += o;
  }
  if (lane == 63) wsum[w] = s;
  __syncthreads();                                         // bar3
  float woff = 0.f;
  #pragma unroll
  for (int k = 0; k < 4; ++k) if (k < w) woff += wsum[k];
  float excl = woff + s - run;
  float y0[16];
  #pragma unroll
  for (int i = 0; i < 16; ++i) {
    float a = fb0 * (excl + p[i]);
    #pragma unroll
    for (int t = 0; t < TAPS; ++t) {
      float vv = (t <= i) ? r[i - t] : h[32 + i - t];
      a += sgs[t] * vv;
    }
    y0[i] = a * x0[i];
  }
  #pragma unroll
  for (int i = 0; i < 16; ++i) buf1[i * 258 + tid + 2] = y0[i];
  __syncthreads();                                         // bar4

  // ---- order 1 ----
  #pragma unroll
  for (int j = 0; j < 32; ++j) h[j] = buf1[(j & 15) * 258 + tid + (j >> 4)];
  run = 0.f;
  #pragma unroll
  for (int i = 0; i < 16; ++i) { run += y0[i]; p[i] = run; }
  s = run;
  #pragma unroll
  for (int off = 1; off < 64; off <<= 1) {
    float o = __shfl_up(s, off);
    if (lane >= off) s += o;
  }
  if (lane == 63) wsum[w] = s;
  __syncthreads();                                         // bar5
  woff = 0.f;
  #pragma unroll
  for (int k = 0; k < 4; ++k) if (k < w) woff += wsum[k];
  excl = woff + s - run;
  unsigned short yout[16];
  #pragma unroll
  for (int i = 0; i < 16; ++i) {
    float a = fb1 * (excl + p[i]);
    #pragma unroll
    for (int t = 0; t < TAPS; ++t) {
      float vv = (t <= i) ? y0[i - t] : h[32 + i - t];
      a += sgs[TAPS + t] * vv;
    }
    yout[i] = f2bf(a * x1[i]);
  }
  unsigned short* outRow = v2T + ((size_t)b * D_DIM + d) * L_SEQ + g;
  *(ushort4*)&outRow[0]  = *(ushort4*)&yout[0];
  *(ushort4*)&outRow[4]  = *(ushort4*)&yout[4];
  *(ushort4*)&outRow[8]  = *(ushort4*)&yout[8];
  *(ushort4*)&outRow[12] = *(ushort4*)&yout[12];
}

// ---------------- v2 transpose: bf16 [b][d][l] -> bf16 [b*l][d] ----------------
__global__ __launch_bounds__(256) void transpose_v2(const unsigned short* __restrict__ src,
                                                    unsigned short* __restrict__ dst) {
  __shared__ unsigned short t[64][66];
  const int l0 = blockIdx.x * 64, d0 = blockIdx.y * 64, b = blockIdx.z;
  const int tx = threadIdx.x & 31, ty = threadIdx.x >> 5;
  const unsigned short* s = src + ((size_t)b * D_DIM + d0) * L_SEQ + l0;
  #pragma unroll
  for (int r = 0; r < 8; ++r) {
    int dd = ty + r * 8;
    *(ushort2*)&t[dd][tx * 2] = *(const ushort2*)&s[(size_t)dd * L_SEQ + tx * 2];
  }
  __syncthreads();
  unsigned short* q = dst + ((size_t)b * L_SEQ + l0) * D_DIM + d0;
  #pragma unroll
  for (int r = 0; r < 8; ++r) {
    int ll = ty + r * 8;
    ushort2 v; v.x = t[tx * 2][ll]; v.y = t[tx * 2 + 1][ll];
    *(ushort2*)&q[(size_t)ll * D_DIM + tx * 2] = v;
  }
}

extern "C" void kernel_launch(void* const* d_in, const int* in_sizes, int n_in,
                              void* d_out, int out_size, void* d_ws, size_t ws_size,
                              hipStream_t stream) {
  (void)in_sizes; (void)n_in; (void)out_size; (void)ws_size;
  const float* u       = (const float*)d_in[0];
  const float* W_in    = (const float*)d_in[1];
  const float* b_in    = (const float*)d_in[2];
  const float* conv_k  = (const float*)d_in[3];
  const float* conv_b  = (const float*)d_in[4];
  const float* W1      = (const float*)d_in[5];
  const float* b1      = (const float*)d_in[6];
  const float* W2      = (const float*)d_in[7];
  const float* b2      = (const float*)d_in[8];
  const float* f_bias  = (const float*)d_in[9];
  const float* f_decay = (const float*)d_in[10];
  const float* W_out   = (const float*)d_in[11];
  const float* b_out   = (const float*)d_in[12];
  float* out = (float*)d_out;

  unsigned short* proj  = (unsigned short*)d_ws;                 // 4*2304*4096 bf16
  unsigned short* v2T   = proj + (size_t)4 * C3 * L_SEQ;         // 4*768*4096 bf16
  unsigned short* ubf   = v2T + (size_t)4 * D_DIM * L_SEQ;       // 16384*768 bf16
  unsigned short* v2F   = ubf;                                   // alias (dead after gemm1)
  unsigned short* W_inT = ubf + (size_t)16384 * 768;
  unsigned short* W_outT= W_inT + (size_t)C3 * D_DIM;
  float* g_tab          = (float*)(W_outT + (size_t)D_DIM * D_DIM);

  static bool g1_attr = false;
  if (!g1_attr) {
    (void)hipFuncSetAttribute(reinterpret_cast<const void*>(gemm1_2ph),
                              hipFuncAttributeMaxDynamicSharedMemorySize, 73728);
    g1_attr = true;
  }

  filt_kernel<<<192, 256, 0, stream>>>(W1, b1, W2, b2, f_decay, g_tab);
  cvt_kernel<<<12288, 256, 0, stream>>>(u, ubf);
  wtrans_kernel<<<dim3(72, 24, 2), 256, 0, stream>>>(W_in, W_inT, W_out, W_outT);
  gemm1_2ph<<<1152, 512, 73728, stream>>>(ubf, W_inT, b_in, proj);
  row_kernel<<<3072, 256, 0, stream>>>(proj, v2T, conv_k, conv_b, g_tab, f_bias);
  transpose_v2<<<dim3(64, 12, 4), 256, 0, stream>>>(v2T, v2F);
  gemm2_mfma<<<dim3(6, 256), 256, 0, stream>>>(v2F, W_outT, b_out, out);
}

// Round 4
// 289.510 us; speedup vs baseline: 1.1252x; 1.0630x over previous
//
#include <hip/hip_runtime.h>
#include <math.h>

#define L_SEQ 4096
#define D_DIM 768
#define C3    2304
#define TAPS  32

typedef __attribute__((ext_vector_type(8))) short bf16x8;
typedef __attribute__((ext_vector_type(4))) float f32x4;

__device__ __forceinline__ unsigned short f2bf(float x) {
  union { float f; unsigned u; } v; v.f = x;
  unsigned r = v.u + 0x7FFF + ((v.u >> 16) & 1);
  return (unsigned short)(r >> 16);
}
__device__ __forceinline__ float bf2f(unsigned short u) {
  union { unsigned u; float f; } v; v.u = ((unsigned)u) << 16; return v.f;
}
__device__ __forceinline__ void gld_lds16(const void* g, void* l) {
  __builtin_amdgcn_global_load_lds((const __attribute__((address_space(1))) void*)g,
                                   (__attribute__((address_space(3))) void*)l, 16, 0, 0);
}

// ---------------- filter: g_tab[c2][t] for t<32 (decay kills lags >=32) ----------------
__global__ __launch_bounds__(256) void filt_kernel(const float* __restrict__ W1,
                                                   const float* __restrict__ b1,
                                                   const float* __restrict__ W2,
                                                   const float* __restrict__ b2,
                                                   const float* __restrict__ f_decay,
                                                   float* __restrict__ g_tab) {
  __shared__ float phi_s[2048];
  const int tid = threadIdx.x;
  #pragma unroll
  for (int it = 0; it < 8; ++it) {
    int idx = tid + it * 256;
    int t = idx >> 6, f = idx & 63;
    float tt = (float)t / 4095.0f;
    float s = b1[f];
    #pragma unroll
    for (int e = 0; e < 33; ++e)
      s += sinf(tt * (float)e * 10.0f) * W1[e * 64 + f];
    phi_s[idx] = sinf(10.0f * s);
  }
  __syncthreads();
  int idx = blockIdx.x * 256 + tid;        // 1536*32
  int c2 = idx >> 5, t = idx & 31;
  float acc = b2[c2];
  #pragma unroll 8
  for (int f = 0; f < 64; ++f)
    acc += phi_s[t * 64 + f] * W2[f * 1536 + c2];
  float r = expf(f_decay[c2]);
  g_tab[idx] = acc * expf(-r * (float)t * (4096.0f / 4095.0f));
}

// ---------------- cvt u: fp32 -> bf16 ----------------
__global__ __launch_bounds__(256) void cvt_kernel(const float* __restrict__ src,
                                                  unsigned short* __restrict__ dst) {
  int idx = (blockIdx.x * 256 + threadIdx.x) * 4;
  float4 v = *(const float4*)&src[idx];
  ushort4 o;
  o.x = f2bf(v.x); o.y = f2bf(v.y); o.z = f2bf(v.z); o.w = f2bf(v.w);
  *(ushort4*)&dst[idx] = o;
}

// ---------------- weight transposes: fp32 [768][C] -> bf16 [C][768] ----------------
__global__ __launch_bounds__(256) void wtrans_kernel(const float* __restrict__ W_in,
                                                     unsigned short* __restrict__ W_inT,
                                                     const float* __restrict__ W_out,
                                                     unsigned short* __restrict__ W_outT) {
  __shared__ float t[32][33];
  const int z = blockIdx.z;
  const float* src = z ? W_out : W_in;
  unsigned short* dst = z ? W_outT : W_inT;
  const int C = z ? 768 : 2304;
  const int c0 = blockIdx.x * 32, r0 = blockIdx.y * 32;
  if (c0 >= C) return;
  const int tx = threadIdx.x & 31, ty = threadIdx.x >> 5;
  #pragma unroll
  for (int rr = 0; rr < 4; ++rr)
    t[ty + rr * 8][tx] = src[(long)(r0 + ty + rr * 8) * C + c0 + tx];
  __syncthreads();
  #pragma unroll
  for (int rr = 0; rr < 4; ++rr)
    dst[(long)(c0 + ty + rr * 8) * 768 + r0 + tx] = f2bf(t[tx][ty + rr * 8]);
}

// ---------------- shared 128x128 MFMA K-step (BK=32, ring-3 16KB slots, T2 swizzle) ----------------
// r3 post-mortem: occupancy is the lever (1blk=97us, 2blk=78us). This config: 48KB LDS,
// 256 thr -> 3 blocks/CU; cross-block wave diversity hides vmcnt/barrier stalls.
// Slot: A [128][32] @+0 (8KB), B [128][32] @+8192. 4 gld_lds/step -> steady vmcnt(4).
// Swizzle (r2-verified, conflicts 5.3M->0.59M): LDS[row][c16] = G[row][c16 ^ ((row>>1)&3)];
// stage src col pre-swizzled (q_src), read csel swizzled; (row>>1)&3 == (fm>>1)&3 since
// all read-row bases are multiples of 16.
__device__ __forceinline__ void g_vmwait(int VM) {
  if (VM == 4)      asm volatile("s_waitcnt vmcnt(4)" ::: "memory");
  else if (VM == 0) asm volatile("s_waitcnt vmcnt(0)" ::: "memory");
}

template<bool STG, int VM>
__device__ __forceinline__ void g_step(int scur, int sstg, int kt, char* smemc, int tid,
                                       int wm64, int wn64, int fm, int csel,
                                       const unsigned short* aP, const unsigned short* bP,
                                       f32x4 (&acc)[4][4]) {
  const unsigned short* As = (const unsigned short*)(smemc + scur * 16384);
  const unsigned short* Bs = (const unsigned short*)(smemc + scur * 16384 + 8192);
  bf16x8 af[4], bfr[4];
  #pragma unroll
  for (int i = 0; i < 4; ++i) af[i]  = *(const bf16x8*)&As[(wm64 + i * 16 + fm) * 32 + csel];
  #pragma unroll
  for (int jj = 0; jj < 4; ++jj) bfr[jj] = *(const bf16x8*)&Bs[(wn64 + jj * 16 + fm) * 32 + csel];
  if (STG) {  // stage K-step kt+2 into slot sstg (slot last read at kt-1, fenced by its barrier)
    const unsigned short* ap = aP + (kt + 2) * 32;
    const unsigned short* bp = bP + (kt + 2) * 32;
    char* d = smemc + sstg * 16384 + tid * 16;
    gld_lds16(ap,         d);            // A rows 0..63
    gld_lds16(ap + 49152, d + 4096);     // A rows 64..127 (64*768)
    gld_lds16(bp,         d + 8192);     // B rows 0..63
    gld_lds16(bp + 49152, d + 12288);    // B rows 64..127
  }
  asm volatile("" ::: "memory");
  __builtin_amdgcn_s_barrier();
  __builtin_amdgcn_s_setprio(1);
  __builtin_amdgcn_sched_barrier(0);
  #pragma unroll
  for (int i = 0; i < 4; ++i)
    #pragma unroll
    for (int jj = 0; jj < 4; ++jj)
      acc[i][jj] = __builtin_amdgcn_mfma_f32_16x16x32_bf16(af[i], bfr[jj], acc[i][jj], 0, 0, 0);
  __builtin_amdgcn_sched_barrier(0);
  __builtin_amdgcn_s_setprio(0);
  g_vmwait(VM);
  asm volatile("" ::: "memory");
  __builtin_amdgcn_s_barrier();
}

// K-loop driver (24 steps of BK=32 over K=768), shared by both GEMMs.
__device__ __forceinline__ void g_kloop(char* smemc, int tid, int wm64, int wn64, int fm,
                                        int csel, const unsigned short* aP,
                                        const unsigned short* bP, f32x4 (&acc)[4][4]) {
  #pragma unroll
  for (int kt = 0; kt < 2; ++kt) {
    char* d = smemc + kt * 16384 + tid * 16;
    const unsigned short* ap = aP + kt * 32;
    const unsigned short* bp = bP + kt * 32;
    gld_lds16(ap,         d);
    gld_lds16(ap + 49152, d + 4096);
    gld_lds16(bp,         d + 8192);
    gld_lds16(bp + 49152, d + 12288);
  }
  asm volatile("s_waitcnt vmcnt(4)" ::: "memory");
  asm volatile("" ::: "memory");
  __builtin_amdgcn_s_barrier();
  int scur = 0;
  #pragma unroll 1
  for (int kt = 0; kt < 22; ++kt) {
    int sstg = scur + 2; if (sstg >= 3) sstg -= 3;
    g_step<true, 4>(scur, sstg, kt, smemc, tid, wm64, wn64, fm, csel, aP, bP, acc);
    scur = (scur == 2) ? 0 : scur + 1;
  }
  {
    int sstg = scur + 2; if (sstg >= 3) sstg -= 3;
    g_step<false, 0>(scur, sstg, 22, smemc, tid, wm64, wn64, fm, csel, aP, bP, acc);
    scur = (scur == 2) ? 0 : scur + 1;
  }
  g_step<false, -1>(scur, 0, 23, smemc, tid, wm64, wn64, fm, csel, aP, bP, acc);
}

// ---------------- GEMM1: u@W_in + b_in -> proj bf16 [b][c][l] ----------------
__global__ __launch_bounds__(256, 3) void gemm1_k3(const unsigned short* __restrict__ A,
                                                   const unsigned short* __restrict__ Bt,
                                                   const float* __restrict__ bias,
                                                   unsigned short* __restrict__ proj) {
  extern __shared__ char smemc[];          // 49152 B dynamic (3 x 16384)
  const int tid = threadIdx.x;
  const int w = tid >> 6, lane = tid & 63;
  // XCD swizzle: 2304 blocks (128 m x 18 n), 2304%8==0 bijective; XCD owns 16-m-tile band.
  const int id = blockIdx.x;
  const int x8 = id & 7, jb = id >> 3;            // jb in [0,288)
  const int mt = x8 * 16 + jb / 18, nt = jb % 18;
  const int m0 = mt * 128, n0 = nt * 128;
  const int wm64 = (w & 1) * 64, wn64 = (w >> 1) * 64;
  const int fm = lane & 15;
  const int csel = (((lane >> 4) ^ ((fm >> 1) & 3)) << 3);
  const int q_src = ((tid & 3) ^ ((tid >> 3) & 3)) * 8;
  const unsigned short* aP = A  + (size_t)(m0 + (tid >> 2)) * 768 + q_src;
  const unsigned short* bP = Bt + (size_t)(n0 + (tid >> 2)) * 768 + q_src;
  f32x4 acc[4][4] = {};
  g_kloop(smemc, tid, wm64, wn64, fm, csel, aP, bP, acc);

  // epilogue: LDS-transpose (16x68-padded, r2/r3-verified) -> coalesced ushort4 runs along l
  const int b = m0 >> 12, l0 = m0 & 4095;
  float* fbuf = (float*)smemc + w * 1088;   // 16 x 68 per wave
  const int fk = lane >> 4;                 // 0..3
  #pragma unroll
  for (int j2 = 0; j2 < 4; ++j2) {
    __syncthreads();
    #pragma unroll
    for (int i = 0; i < 4; ++i)
      *(f32x4*)&fbuf[fm * 68 + i * 16 + fk * 4] = acc[i][j2];
    __syncthreads();
    #pragma unroll
    for (int p = 0; p < 4; ++p) {
      int nl = p * 4 + fk;
      int c = n0 + wn64 + j2 * 16 + nl;
      float4 v = *(float4*)&fbuf[nl * 68 + fm * 4];
      float bb = bias[c];
      ushort4 o;
      o.x = f2bf(v.x + bb); o.y = f2bf(v.y + bb);
      o.z = f2bf(v.z + bb); o.w = f2bf(v.w + bb);
      *(ushort4*)&proj[((size_t)b * C3 + c) * L_SEQ + l0 + wm64 + fm * 4] = o;
    }
  }
}

// ---------------- GEMM2: v2F@W_out + b_out -> out f32 [b*l][d] ----------------
__global__ __launch_bounds__(256, 3) void gemm2_k3(const unsigned short* __restrict__ A,
                                                   const unsigned short* __restrict__ Bt,
                                                   const float* __restrict__ bias,
                                                   float* __restrict__ out) {
  extern __shared__ char smemc[];          // 49152 B dynamic
  const int tid = threadIdx.x;
  const int w = tid >> 6, lane = tid & 63;
  // 768 blocks (128 m x 6 n) = exactly 3/CU x 256 CU, single occupancy round; 768%8==0.
  const int id = blockIdx.x;
  const int x8 = id & 7, jb = id >> 3;            // jb in [0,96)
  const int mt = x8 * 16 + jb / 6, nt = jb % 6;
  const int m0 = mt * 128, n0 = nt * 128;
  const int wm64 = (w & 1) * 64, wn64 = (w >> 1) * 64;
  const int fm = lane & 15;
  const int csel = (((lane >> 4) ^ ((fm >> 1) & 3)) << 3);
  const int q_src = ((tid & 3) ^ ((tid >> 3) & 3)) * 8;
  const unsigned short* aP = A  + (size_t)(m0 + (tid >> 2)) * 768 + q_src;
  const unsigned short* bP = Bt + (size_t)(n0 + (tid >> 2)) * 768 + q_src;
  f32x4 acc[4][4] = {};
  g_kloop(smemc, tid, wm64, wn64, fm, csel, aP, bP, acc);

  // epilogue (r3-gemm2-verified pattern): f32 out, 256B-contiguous stores along n
  float* fbuf = (float*)smemc + w * 1088;   // 16 x 68 per wave
  const int fk = lane >> 4;
  const int nf = lane & 15, mq = lane >> 4;
  float4 bb4 = *(const float4*)&bias[n0 + wn64 + nf * 4];
  #pragma unroll
  for (int i = 0; i < 4; ++i) {
    __syncthreads();
    #pragma unroll
    for (int cg = 0; cg < 4; ++cg)
      #pragma unroll
      for (int r = 0; r < 4; ++r)
        fbuf[(fk * 4 + r) * 68 + cg * 16 + fm] = acc[i][cg][r];
    __syncthreads();
    #pragma unroll
    for (int pass = 0; pass < 4; ++pass) {
      int m_l = pass * 4 + mq;
      float4 v = *(float4*)&fbuf[m_l * 68 + nf * 4];
      v.x += bb4.x; v.y += bb4.y; v.z += bb4.z; v.w += bb4.w;
      *(float4*)&out[(size_t)(m0 + wm64 + i * 16 + m_l) * D_DIM + n0 + wn64 + nf * 4] = v;
    }
  }
}

// ---------------- row kernel: conflict-free column LDS + shfl scan ----------------
__global__ __launch_bounds__(256) void row_kernel(const unsigned short* __restrict__ proj,
                                                  unsigned short* __restrict__ v2T,
                                                  const float* __restrict__ conv_k,
                                                  const float* __restrict__ conv_b,
                                                  const float* __restrict__ g_tab,
                                                  const float* __restrict__ f_bias) {
  __shared__ float buf0[4128];
  __shared__ float buf1[4128];
  __shared__ float sgs[2 * TAPS];
  __shared__ float wsum[4];
  __shared__ float bnd[3][4][2];
  const int tid = threadIdx.x;
  const int lane = tid & 63, w = tid >> 6;
  const int b = blockIdx.x / D_DIM, d = blockIdx.x % D_DIM;
  const int g = tid * 16;

  const unsigned short* rowV  = proj + ((size_t)b * C3 + 2 * D_DIM + d) * L_SEQ;
  const unsigned short* rowX0 = proj + ((size_t)b * C3 + d) * L_SEQ;
  const unsigned short* rowX1 = proj + ((size_t)b * C3 + D_DIM + d) * L_SEQ;

  float v[16], x0[16], x1[16];
  #pragma unroll
  for (int k = 0; k < 4; ++k) {
    ushort4 qv = *(const ushort4*)&rowV[g + k * 4];
    v[k * 4] = bf2f(qv.x); v[k * 4 + 1] = bf2f(qv.y); v[k * 4 + 2] = bf2f(qv.z); v[k * 4 + 3] = bf2f(qv.w);
    ushort4 q0 = *(const ushort4*)&rowX0[g + k * 4];
    x0[k * 4] = bf2f(q0.x); x0[k * 4 + 1] = bf2f(q0.y); x0[k * 4 + 2] = bf2f(q0.z); x0[k * 4 + 3] = bf2f(q0.w);
    ushort4 q1 = *(const ushort4*)&rowX1[g + k * 4];
    x1[k * 4] = bf2f(q1.x); x1[k * 4 + 1] = bf2f(q1.y); x1[k * 4 + 2] = bf2f(q1.z); x1[k * 4 + 3] = bf2f(q1.w);
  }

  if (tid < 32) {
    int ph = (tid & 15) * 258 + (tid >> 4);
    buf0[ph] = 0.f; buf1[ph] = 0.f;
  }
  if (tid < 64) sgs[tid] = g_tab[((size_t)((tid >> 5) * D_DIM + d)) * TAPS + (tid & 31)];
  if (lane == 63) {
    bnd[0][w][0] = v[14];  bnd[0][w][1] = v[15];
    bnd[1][w][0] = x0[14]; bnd[1][w][1] = x0[15];
    bnd[2][w][0] = x1[14]; bnd[2][w][1] = x1[15];
  }
  const int cv = 2 * D_DIM + d, cx0 = d, cx1 = D_DIM + d;
  const float kv0 = conv_k[cv],  kv1 = conv_k[C3 + cv],  kv2 = conv_k[2 * C3 + cv],  bv = conv_b[cv];
  const float ka0 = conv_k[cx0], ka1 = conv_k[C3 + cx0], ka2 = conv_k[2 * C3 + cx0], ba = conv_b[cx0];
  const float kb0 = conv_k[cx1], kb1 = conv_k[C3 + cx1], kb2 = conv_k[2 * C3 + cx1], bb = conv_b[cx1];
  const float fb0 = f_bias[d], fb1 = f_bias[D_DIM + d];
  __syncthreads();                                         // bar1

  float vm1 = __shfl_up(v[15], 1),  vm2 = __shfl_up(v[14], 1);
  float am1 = __shfl_up(x0[15], 1), am2 = __shfl_up(x0[14], 1);
  float bm1 = __shfl_up(x1[15], 1), bm2 = __shfl_up(x1[14], 1);
  if (lane == 0) {
    if (w > 0) {
      vm2 = bnd[0][w-1][0]; vm1 = bnd[0][w-1][1];
      am2 = bnd[1][w-1][0]; am1 = bnd[1][w-1][1];
      bm2 = bnd[2][w-1][0]; bm1 = bnd[2][w-1][1];
    } else {
      vm1 = vm2 = am1 = am2 = bm1 = bm2 = 0.f;
    }
  }
  float r[16];
  r[0] = vm2 * kv0 + vm1 * kv1 + v[0] * kv2 + bv;
  r[1] = vm1 * kv0 + v[0] * kv1 + v[1] * kv2 + bv;
  #pragma unroll
  for (int i = 2; i < 16; ++i) r[i] = v[i-2] * kv0 + v[i-1] * kv1 + v[i] * kv2 + bv;
  {
    float t0 = am2 * ka0 + am1 * ka1 + x0[0] * ka2 + ba;
    float t1 = am1 * ka0 + x0[0] * ka1 + x0[1] * ka2 + ba;
    #pragma unroll
    for (int i = 15; i >= 2; --i) x0[i] = x0[i-2] * ka0 + x0[i-1] * ka1 + x0[i] * ka2 + ba;
    x0[0] = t0; x0[1] = t1;
  }
  {
    float t0 = bm2 * kb0 + bm1 * kb1 + x1[0] * kb2 + bb;
    float t1 = bm1 * kb0 + x1[0] * kb1 + x1[1] * kb2 + bb;
    #pragma unroll
    for (int i = 15; i >= 2; --i) x1[i] = x1[i-2] * kb0 + x1[i-1] * kb1 + x1[i] * kb2 + bb;
    x1[0] = t0; x1[1] = t1;
  }
  #pragma unroll
  for (int i = 0; i < 16; ++i) buf0[i * 258 + tid + 2] = r[i];
  __syncthreads();                                         // bar2

  // ---- order 0 ----
  float h[32];
  #pragma unroll
  for (int j = 0; j < 32; ++j) h[j] = buf0[(j & 15) * 258 + tid + (j >> 4)];
  float p[16], run = 0.f;
  #pragma unroll
  for (int i = 0; i < 16; ++i) { run += r[i]; p[i] = run; }
  float s = run;
  #pragma unroll
  for (int off = 1; off < 64; off <<= 1) {
    float o = __shfl_up(s, off);
    if (lane >= off) s += o;
  }
  if (lane == 63) wsum[w] = s;
  __syncthreads();                                         // bar3
  float woff = 0.f;
  #pragma unroll
  for (int k = 0; k < 4; ++k) if (k < w) woff += wsum[k];
  float excl = woff + s - run;
  float y0[16];
  #pragma unroll
  for (int i = 0; i < 16; ++i) {
    float a = fb0 * (excl + p[i]);
    #pragma unroll
    for (int t = 0; t < TAPS; ++t) {
      float vv = (t <= i) ? r[i - t] : h[32 + i - t];
      a += sgs[t] * vv;
    }
    y0[i] = a * x0[i];
  }
  #pragma unroll
  for (int i = 0; i < 16; ++i) buf1[i * 258 + tid + 2] = y0[i];
  __syncthreads();                                         // bar4

  // ---- order 1 ----
  #pragma unroll
  for (int j = 0; j < 32; ++j) h[j] = buf1[(j & 15) * 258 + tid + (j >> 4)];
  run = 0.f;
  #pragma unroll
  for (int i = 0; i < 16; ++i) { run += y0[i]; p[i] = run; }
  s = run;
  #pragma unroll
  for (int off = 1; off < 64; off <<= 1) {
    float o = __shfl_up(s, off);
    if (lane >= off) s += o;
  }
  if (lane == 63) wsum[w] = s;
  __syncthreads();                                         // bar5
  woff = 0.f;
  #pragma unroll
  for (int k = 0; k < 4; ++k) if (k < w) woff += wsum[k];
  excl = woff + s - run;
  unsigned short yout[16];
  #pragma unroll
  for (int i = 0; i < 16; ++i) {
    float a = fb1 * (excl + p[i]);
    #pragma unroll
    for (int t = 0; t < TAPS; ++t) {
      float vv = (t <= i) ? y0[i - t] : h[32 + i - t];
      a += sgs[TAPS + t] * vv;
    }
    yout[i] = f2bf(a * x1[i]);
  }
  unsigned short* outRow = v2T + ((size_t)b * D_DIM + d) * L_SEQ + g;
  *(ushort4*)&outRow[0]  = *(ushort4*)&yout[0];
  *(ushort4*)&outRow[4]  = *(ushort4*)&yout[4];
  *(ushort4*)&outRow[8]  = *(ushort4*)&yout[8];
  *(ushort4*)&outRow[12] = *(ushort4*)&yout[12];
}

// ---------------- v2 transpose: bf16 [b][d][l] -> bf16 [b*l][d] ----------------
__global__ __launch_bounds__(256) void transpose_v2(const unsigned short* __restrict__ src,
                                                    unsigned short* __restrict__ dst) {
  __shared__ unsigned short t[64][66];
  const int l0 = blockIdx.x * 64, d0 = blockIdx.y * 64, b = blockIdx.z;
  const int tx = threadIdx.x & 31, ty = threadIdx.x >> 5;
  const unsigned short* s = src + ((size_t)b * D_DIM + d0) * L_SEQ + l0;
  #pragma unroll
  for (int r = 0; r < 8; ++r) {
    int dd = ty + r * 8;
    *(ushort2*)&t[dd][tx * 2] = *(const ushort2*)&s[(size_t)dd * L_SEQ + tx * 2];
  }
  __syncthreads();
  unsigned short* q = dst + ((size_t)b * L_SEQ + l0) * D_DIM + d0;
  #pragma unroll
  for (int r = 0; r < 8; ++r) {
    int ll = ty + r * 8;
    ushort2 v; v.x = t[tx * 2][ll]; v.y = t[tx * 2 + 1][ll];
    *(ushort2*)&q[(size_t)ll * D_DIM + tx * 2] = v;
  }
}

extern "C" void kernel_launch(void* const* d_in, const int* in_sizes, int n_in,
                              void* d_out, int out_size, void* d_ws, size_t ws_size,
                              hipStream_t stream) {
  (void)in_sizes; (void)n_in; (void)out_size; (void)ws_size;
  const float* u       = (const float*)d_in[0];
  const float* W_in    = (const float*)d_in[1];
  const float* b_in    = (const float*)d_in[2];
  const float* conv_k  = (const float*)d_in[3];
  const float* conv_b  = (const float*)d_in[4];
  const float* W1      = (const float*)d_in[5];
  const float* b1      = (const float*)d_in[6];
  const float* W2      = (const float*)d_in[7];
  const float* b2      = (const float*)d_in[8];
  const float* f_bias  = (const float*)d_in[9];
  const float* f_decay = (const float*)d_in[10];
  const float* W_out   = (const float*)d_in[11];
  const float* b_out   = (const float*)d_in[12];
  float* out = (float*)d_out;

  unsigned short* proj  = (unsigned short*)d_ws;                 // 4*2304*4096 bf16
  unsigned short* v2T   = proj + (size_t)4 * C3 * L_SEQ;         // 4*768*4096 bf16
  unsigned short* ubf   = v2T + (size_t)4 * D_DIM * L_SEQ;       // 16384*768 bf16
  unsigned short* v2F   = ubf;                                   // alias (dead after gemm1)
  unsigned short* W_inT = ubf + (size_t)16384 * 768;
  unsigned short* W_outT= W_inT + (size_t)C3 * D_DIM;
  float* g_tab          = (float*)(W_outT + (size_t)D_DIM * D_DIM);

  static bool g_attr = false;
  if (!g_attr) {
    (void)hipFuncSetAttribute(reinterpret_cast<const void*>(gemm1_k3),
                              hipFuncAttributeMaxDynamicSharedMemorySize, 49152);
    (void)hipFuncSetAttribute(reinterpret_cast<const void*>(gemm2_k3),
                              hipFuncAttributeMaxDynamicSharedMemorySize, 49152);
    g_attr = true;
  }

  filt_kernel<<<192, 256, 0, stream>>>(W1, b1, W2, b2, f_decay, g_tab);
  cvt_kernel<<<12288, 256, 0, stream>>>(u, ubf);
  wtrans_kernel<<<dim3(72, 24, 2), 256, 0, stream>>>(W_in, W_inT, W_out, W_outT);
  gemm1_k3<<<2304, 256, 49152, stream>>>(ubf, W_inT, b_in, proj);
  row_kernel<<<3072, 256, 0, stream>>>(proj, v2T, conv_k, conv_b, g_tab, f_bias);
  transpose_v2<<<dim3(64, 12, 4), 256, 0, stream>>>(v2T, v2F);
  gemm2_k3<<<768, 256, 49152, stream>>>(v2F, W_outT, b_out, out);
}